// Round 10
// baseline (362.004 us; speedup 1.0000x reference)
//
#include <hip/hip_runtime.h>
#include <stdint.h>

// ---- problem constants ----
#define NB 16        // batch
#define NN 4096      // nodes
#define DD 64        // feature dim (== S)
#define EE 32768     // edges (before self loops)
#define ETOT 36864   // edges + self loops
#define ROWS 65536   // B*N
#define KSPLIT 2

typedef _Float16 f16;
typedef f16   half8 __attribute__((ext_vector_type(8)));
typedef f16   f16x8 __attribute__((ext_vector_type(8)));
typedef f16   f16x4 __attribute__((ext_vector_type(4)));
typedef float f32x4 __attribute__((ext_vector_type(4)));

__device__ __forceinline__ void gload16(const f16* g, f16* l) {
  __builtin_amdgcn_global_load_lds((const __attribute__((address_space(1))) void*)g,
                                   (__attribute__((address_space(3))) void*)l, 16, 0, 0);
}

// ---------------- CSR build ----------------
__global__ __launch_bounds__(256) void k_zero(int* p, int n) {
  int i = blockIdx.x * 256 + threadIdx.x;
  if (i < n) p[i] = 0;
}

__global__ __launch_bounds__(256) void k_count(const int* __restrict__ ei, int* __restrict__ cnt) {
  int t = blockIdx.x * 256 + threadIdx.x;
  if (t >= ETOT) return;
  int d = (t < EE) ? ei[EE + t] : (t - EE);
  atomicAdd(&cnt[d], 1);
}

__global__ __launch_bounds__(256) void k_scan(const int* __restrict__ cnt, int* __restrict__ offs) {
  __shared__ int part[256];
  int t = threadIdx.x;
  int loc[16]; int s = 0;
  #pragma unroll
  for (int i = 0; i < 16; ++i) { int v = cnt[(t << 4) + i]; loc[i] = s; s += v; }
  part[t] = s;
  __syncthreads();
  int own = s;
  for (int d = 1; d < 256; d <<= 1) {
    int u = (t >= d) ? part[t - d] : 0;
    __syncthreads();
    part[t] += u;
    __syncthreads();
  }
  int base = part[t] - own;
  #pragma unroll
  for (int i = 0; i < 16; ++i) offs[(t << 4) + i] = base + loc[i];
}

__global__ __launch_bounds__(256) void k_fill(const int* __restrict__ ei, const int* __restrict__ offs,
                                              int* __restrict__ cur, int* __restrict__ esrc,
                                              int* __restrict__ edst) {
  int t = blockIdx.x * 256 + threadIdx.x;
  if (t >= ETOT) return;
  int s, d;
  if (t < EE) { s = ei[t]; d = ei[EE + t]; } else { s = d = t - EE; }
  int p = atomicAdd(&cur[d], 1);
  esrc[offs[d] + p] = s;
  edst[offs[d] + p] = d;
}

// ---------------- seq_linear: h = in^T @ Wseq + b + in^T  (+ fused HT write) ----------------
__global__ __launch_bounds__(256) void k_seq(const float* __restrict__ inp, const float* __restrict__ Wseq,
                                             const float* __restrict__ bseq, float* __restrict__ h,
                                             f16* __restrict__ HT) {
  __shared__ float X[64 * 68];
  int t = threadIdx.x;
  int b = blockIdx.x >> 6, n0 = (blockIdx.x & 63) << 6;
  #pragma unroll
  for (int i = 0; i < 16; ++i) {
    int idx = t + (i << 8);
    int s = idx >> 6, nl = idx & 63;
    X[nl * 68 + s] = inp[((size_t)((b << 6) + s) << 12) + n0 + nl];
  }
  __syncthreads();
  int c = t & 63, rg = t >> 6;
  float Wc[64];
  #pragma unroll
  for (int k = 0; k < 64; ++k) Wc[k] = Wseq[(k << 6) + c];
  float bc = bseq[c];
  float av[16];
  for (int rr = 0; rr < 16; ++rr) {
    int r = (rg << 4) + rr;
    float a = bc + X[r * 68 + c];
    #pragma unroll
    for (int k4 = 0; k4 < 16; ++k4) {
      float4 x = *(const float4*)&X[r * 68 + (k4 << 2)];
      a = fmaf(x.x, Wc[4*k4+0], a); a = fmaf(x.y, Wc[4*k4+1], a);
      a = fmaf(x.z, Wc[4*k4+2], a); a = fmaf(x.w, Wc[4*k4+3], a);
    }
    h[((size_t)(b << 12) + n0 + r) * 64 + c] = a;
    av[rr] = a;
  }
  __syncthreads();
  #pragma unroll
  for (int rr = 0; rr < 16; ++rr) X[((rg << 4) + rr) * 68 + c] = av[rr];
  __syncthreads();
  int nl = t & 63, dg = t >> 6;
  #pragma unroll
  for (int i = 0; i < 16; ++i) {
    int d = (dg << 4) + i;
    HT[((size_t)((b << 6) + d) << 12) + n0 + nl] = (f16)X[nl * 68 + d];
  }
}

// ---------------- adjacency prep: casts ----------------
__global__ __launch_bounds__(256) void k_castSE(const float* __restrict__ SE, f16* __restrict__ SEh) {
  int i = (blockIdx.x * 256 + threadIdx.x) * 4;
  float4 v = *(const float4*)(SE + i);
  f16 o[4] = {(f16)v.x, (f16)v.y, (f16)v.z, (f16)v.w};
  *(uint64_t*)(SEh + i) = *(uint64_t*)o;
}

__global__ __launch_bounds__(256) void k_castTE(const float* __restrict__ TE, f16* __restrict__ TEh) {
  __shared__ float X[64 * 65];
  int t = threadIdx.x;
  int j0 = blockIdx.x << 6;
  #pragma unroll
  for (int i = 0; i < 16; ++i) {
    int idx = t + (i << 8);           // 0..4095 = 64k x 64j
    int k = idx >> 6, jl = idx & 63;
    X[jl * 65 + k] = TE[((size_t)k << 12) + j0 + jl];
  }
  __syncthreads();
  int jl = t >> 2, kg = t & 3;        // 4 threads per output row, 16 k each
  f16 o[16];
  #pragma unroll
  for (int i = 0; i < 16; ++i) o[i] = (f16)X[jl * 65 + (kg << 4) + i];
  f16* dst = TEh + ((size_t)(j0 + jl) << 6) + (kg << 4);
  *(uint64_t*)(dst + 0) = *(uint64_t*)(o + 0);
  *(uint64_t*)(dst + 4) = *(uint64_t*)(o + 4);
  *(uint64_t*)(dst + 8) = *(uint64_t*)(o + 8);
  *(uint64_t*)(dst + 12) = *(uint64_t*)(o + 12);
}

// ---------------- adjacency MFMA GEMM: A = exp(relu(SEh @ TEh^T)) (raw), row partial sums ----------------
__global__ __launch_bounds__(256) void k_adjmm(const f16* __restrict__ SEh, const f16* __restrict__ TEh,
                                               f16* __restrict__ A, float* __restrict__ Zpart) {
  __shared__ f16 Al[128 * 32];
  __shared__ f16 Bl[128 * 32];
  const int t = threadIdx.x, lane = t & 63, w = t >> 6;
  const int m0 = blockIdx.y << 7, j0 = blockIdx.x << 7;
  const int l15 = lane & 15, lhi = lane >> 4;
  const int wm = (w >> 1) << 6, wj = (w & 1) << 6;
  f32x4 acc[4][4] = {};
  const int c0 = (w << 6) + lane;
  const int row0 = c0 >> 2, ko0 = (c0 & 3) << 3;
  const int c1 = c0 + 256;
  const int row1 = c1 >> 2, ko1 = (c1 & 3) << 3;
  const f16* ga0 = SEh + (size_t)(m0 + row0) * 64 + ko0;
  const f16* ga1 = SEh + (size_t)(m0 + row1) * 64 + ko1;
  const f16* gb0 = TEh + (size_t)(j0 + row0) * 64 + ko0;
  const f16* gb1 = TEh + (size_t)(j0 + row1) * 64 + ko1;
  f16* la0 = Al + c0 * 8; f16* la1 = Al + c1 * 8;
  f16* lb0 = Bl + c0 * 8; f16* lb1 = Bl + c1 * 8;
  for (int kt = 0; kt < 2; ++kt) {
    const int kof = kt << 5;
    gload16(ga0 + kof, la0);
    gload16(ga1 + kof, la1);
    gload16(gb0 + kof, lb0);
    gload16(gb1 + kof, lb1);
    __syncthreads();
    half8 af[4], bf[4];
    #pragma unroll
    for (int i = 0; i < 4; ++i) {
      af[i] = *(const half8*)(Al + (wm + i * 16 + l15) * 32 + lhi * 8);
      bf[i] = *(const half8*)(Bl + (wj + i * 16 + l15) * 32 + lhi * 8);
    }
    #pragma unroll
    for (int mi = 0; mi < 4; ++mi)
      #pragma unroll
      for (int nj = 0; nj < 4; ++nj)
        acc[mi][nj] = __builtin_amdgcn_mfma_f32_16x16x32_f16(af[mi], bf[nj], acc[mi][nj], 0, 0, 0);
    __syncthreads();
  }
  float rs[4][4];
  #pragma unroll
  for (int mi = 0; mi < 4; ++mi)
    #pragma unroll
    for (int r = 0; r < 4; ++r) rs[mi][r] = 0.f;
  #pragma unroll
  for (int mi = 0; mi < 4; ++mi)
    #pragma unroll
    for (int nj = 0; nj < 4; ++nj)
      #pragma unroll
      for (int r = 0; r < 4; ++r) {
        int row = m0 + wm + mi * 16 + lhi * 4 + r;
        int col = j0 + wj + nj * 16 + l15;
        float e = __expf(fmaxf(acc[mi][nj][r], 0.f));
        f16 eh = (f16)e;
        A[((size_t)row << 12) + col] = eh;
        rs[mi][r] += (float)eh;      // sum the rounded value for consistency
      }
  #pragma unroll
  for (int mi = 0; mi < 4; ++mi)
    #pragma unroll
    for (int r = 0; r < 4; ++r) {
      float s = rs[mi][r];
      s += __shfl_xor(s, 1); s += __shfl_xor(s, 2);
      s += __shfl_xor(s, 4); s += __shfl_xor(s, 8);
      rs[mi][r] = s;
    }
  if (l15 == 0) {
    int p = (blockIdx.x << 1) + (w & 1);
    #pragma unroll
    for (int mi = 0; mi < 4; ++mi)
      #pragma unroll
      for (int r = 0; r < 4; ++r)
        Zpart[((size_t)p << 12) + m0 + wm + mi * 16 + lhi * 4 + r] = rs[mi][r];
  }
}

__global__ __launch_bounds__(256) void k_rowz(const float* __restrict__ Zpart, float* __restrict__ rowZ) {
  int row = blockIdx.x * 256 + threadIdx.x;
  float s = 0.f;
  #pragma unroll 8
  for (int p = 0; p < 64; ++p) s += Zpart[((size_t)p << 12) + row];
  rowZ[row] = 1.f / s;
}

// ---------------- big GEMM, 8-phase-style schedule (unchanged from R9) ----------------
#define NKT 32
__global__ __launch_bounds__(512) void k_gemm8(const f16* __restrict__ A, const f16* __restrict__ BT,
                                               f16* __restrict__ Cout) {
  extern __shared__ f16 smem[];     // 3 bufs x (A 16384 f16 + B 8192 f16) = 73728 f16
  const int t = threadIdx.x, lane = t & 63, wid = t >> 6;
  const int wr = wid >> 2, wc = wid & 3;
  const int l15 = lane & 15, lhi = lane >> 4;
  const int h7 = l15 & 7;
  const int wgid = blockIdx.x;
  const int nid = (wgid & 7) * 32 + (wgid >> 3);   // 256 wgs, 32 contiguous per XCD
  const int z = nid >> 7, rem = nid & 127;
  const int m0 = (rem >> 3) << 8;                  // 16 m-tiles * 256
  const int j0 = (rem & 7) << 7;                   // 8 j-tiles * 128
  const size_t kbase = (size_t)z << 11;            // K half
  f16* __restrict__ Cz = Cout + ((size_t)z << 22);

  const f16* gA[4]; int lA[4];
  #pragma unroll
  for (int i = 0; i < 4; ++i) {
    int s = t + (i << 9), row = s >> 3, sl = (s & 7) ^ (row & 7);
    gA[i] = A + (size_t)(m0 + row) * 4096 + kbase + sl * 8;
    lA[i] = s * 8;
  }
  const f16* gB[2]; int lB[2];
  #pragma unroll
  for (int i = 0; i < 2; ++i) {
    int s = t + (i << 9), row = s >> 3, sl = (s & 7) ^ (row & 7);
    gB[i] = BT + (size_t)(j0 + row) * 4096 + kbase + sl * 8;
    lB[i] = 16384 + s * 8;
  }
  #define SA(buf, kt, i) gload16(gA[i] + (kt) * 64, smem + (buf) * 24576 + lA[i])
  #define SB(buf, kt, i) gload16(gB[i] + (kt) * 64, smem + (buf) * 24576 + lB[i])

  const int rbase = wr << 7;
  const int cbase = wc << 5;
  f32x4 acc[8][2] = {};

  #pragma unroll
  for (int i = 0; i < 4; ++i) SA(0, 0, i);
  #pragma unroll
  for (int i = 0; i < 2; ++i) SB(0, 0, i);
  #pragma unroll
  for (int i = 0; i < 4; ++i) SA(1, 1, i);
  #pragma unroll
  for (int i = 0; i < 2; ++i) SB(1, 1, i);
  asm volatile("s_waitcnt vmcnt(6)" ::: "memory");
  __builtin_amdgcn_sched_barrier(0);
  __builtin_amdgcn_s_barrier();
  __builtin_amdgcn_sched_barrier(0);

  int b0 = 0, b1 = 1, b2 = 2;
  for (int kt = 0; kt < NKT; ++kt) {
    const f16* Ab = smem + b0 * 24576;
    const f16* Bb = Ab + 16384;
    const bool pf = (kt + 2 < NKT);
    // ---- phase 0 ----
    {
      half8 af[8], bf[2];
      #pragma unroll
      for (int mi = 0; mi < 8; ++mi) {
        int row = rbase + mi * 16 + l15;
        af[mi] = *(const half8*)(Ab + row * 64 + (lhi ^ h7) * 8);
      }
      #pragma unroll
      for (int nj = 0; nj < 2; ++nj) {
        int row = cbase + nj * 16 + l15;
        bf[nj] = *(const half8*)(Bb + row * 64 + (lhi ^ h7) * 8);
      }
      if (pf) { SA(b2, kt + 2, 0); SA(b2, kt + 2, 1); SA(b2, kt + 2, 2); }
      __builtin_amdgcn_s_setprio(1);
      #pragma unroll
      for (int mi = 0; mi < 8; ++mi)
        #pragma unroll
        for (int nj = 0; nj < 2; ++nj)
          acc[mi][nj] = __builtin_amdgcn_mfma_f32_16x16x32_f16(af[mi], bf[nj], acc[mi][nj], 0, 0, 0);
      __builtin_amdgcn_s_setprio(0);
    }
    __builtin_amdgcn_s_barrier();
    __builtin_amdgcn_sched_barrier(0);
    // ---- phase 1 ----
    {
      half8 af[8], bf[2];
      #pragma unroll
      for (int mi = 0; mi < 8; ++mi) {
        int row = rbase + mi * 16 + l15;
        af[mi] = *(const half8*)(Ab + row * 64 + ((4 + lhi) ^ h7) * 8);
      }
      #pragma unroll
      for (int nj = 0; nj < 2; ++nj) {
        int row = cbase + nj * 16 + l15;
        bf[nj] = *(const half8*)(Bb + row * 64 + ((4 + lhi) ^ h7) * 8);
      }
      if (pf) { SA(b2, kt + 2, 3); SB(b2, kt + 2, 0); SB(b2, kt + 2, 1); }
      __builtin_amdgcn_s_setprio(1);
      #pragma unroll
      for (int mi = 0; mi < 8; ++mi)
        #pragma unroll
        for (int nj = 0; nj < 2; ++nj)
          acc[mi][nj] = __builtin_amdgcn_mfma_f32_16x16x32_f16(af[mi], bf[nj], acc[mi][nj], 0, 0, 0);
      __builtin_amdgcn_s_setprio(0);
    }
    if (kt < NKT - 2)       asm volatile("s_waitcnt vmcnt(6)" ::: "memory");
    else if (kt == NKT - 2) asm volatile("s_waitcnt vmcnt(0)" ::: "memory");
    __builtin_amdgcn_sched_barrier(0);
    __builtin_amdgcn_s_barrier();
    __builtin_amdgcn_sched_barrier(0);
    int tb = b0; b0 = b1; b1 = b2; b2 = tb;
  }
  #undef SA
  #undef SB
  #pragma unroll
  for (int mi = 0; mi < 8; ++mi)
    #pragma unroll
    for (int nj = 0; nj < 2; ++nj)
      #pragma unroll
      for (int r = 0; r < 4; ++r) {
        int row = m0 + rbase + mi * 16 + (lhi << 2) + r;
        int col = j0 + cbase + nj * 16 + l15;
        Cz[(size_t)row * 1024 + col] = (f16)acc[mi][nj][r];
      }
}

// ---------------- Wgh prep: B^T for xp-GEMM, padded with va/vd columns ----------------
template<int H, int NP>
__global__ __launch_bounds__(256) void k_wprep(const float* __restrict__ Wg, const float* __restrict__ asrc,
                                               const float* __restrict__ adst, f16* __restrict__ Wgh) {
  for (int i = blockIdx.x * 256 + threadIdx.x; i < NP * 64; i += 16 * 256) {
    int j = i >> 6, k = i & 63;
    float v;
    if (j < H * 64) {
      v = Wg[(size_t)k * (H * 64) + j];
    } else if (j < H * 64 + 2 * H) {
      int cc = j - H * 64, hh = cc >> 1;
      const float* a = ((cc & 1) ? adst : asrc) + (hh << 6);
      const float* wrow = Wg + (size_t)k * (H * 64) + (hh << 6);
      float s = 0.f;
      #pragma unroll 16
      for (int c = 0; c < 64; ++c) s = fmaf(wrow[c], a[c], s);
      v = s;
    } else v = 0.f;
    Wgh[(size_t)j * 64 + k] = (f16)v;
  }
}

// ---------------- xp = h @ Wg via MFMA (f16 out) + als/ald from padded columns ----------------
template<int H, int NP>
__global__ __launch_bounds__(256) void k_xpmm(const float* __restrict__ h, const f16* __restrict__ Wgh,
                                              f16* __restrict__ xp, float* __restrict__ als,
                                              float* __restrict__ ald) {
  __shared__ f16 Ah[128 * 72];
  __shared__ f16 Bh[NP * 72];
  const int t = threadIdx.x, lane = t & 63, w = t >> 6;
  const size_t r0 = (size_t)blockIdx.x * 128;
  #pragma unroll
  for (int i = 0; i < 8; ++i) {
    int idx = t + (i << 8);
    int row = idx >> 4, k4 = (idx & 15) << 2;
    float4 v = *(const float4*)&h[(r0 + row) * 64 + k4];
    f16 o[4] = {(f16)v.x, (f16)v.y, (f16)v.z, (f16)v.w};
    *(uint64_t*)&Ah[row * 72 + k4] = *(uint64_t*)o;
  }
  for (int i = t; i < NP * 16; i += 256) {
    int row = i >> 4, k4 = (i & 15) << 2;
    *(uint64_t*)&Bh[row * 72 + k4] = *(const uint64_t*)&Wgh[(size_t)row * 64 + k4];
  }
  __syncthreads();
  const int l15 = lane & 15, lhi = lane >> 4;
  const int NT = NP / 16;
  f32x4 acc[2][NT] = {};
  #pragma unroll
  for (int kk = 0; kk < 2; ++kk) {
    half8 af[2], bf[NT];
    #pragma unroll
    for (int i = 0; i < 2; ++i)
      af[i] = *(const half8*)&Ah[(w * 32 + i * 16 + l15) * 72 + kk * 32 + lhi * 8];
    #pragma unroll
    for (int j = 0; j < NT; ++j)
      bf[j] = *(const half8*)&Bh[(j * 16 + l15) * 72 + kk * 32 + lhi * 8];
    #pragma unroll
    for (int i = 0; i < 2; ++i)
      #pragma unroll
      for (int j = 0; j < NT; ++j)
        acc[i][j] = __builtin_amdgcn_mfma_f32_16x16x32_f16(af[i], bf[j], acc[i][j], 0, 0, 0);
  }
  #pragma unroll
  for (int i = 0; i < 2; ++i) {
    int rloc = w * 32 + i * 16 + lhi * 4;
    #pragma unroll
    for (int j = 0; j < NT; ++j) {
      #pragma unroll
      for (int r = 0; r < 4; ++r) {
        int col = j * 16 + l15;
        size_t row = r0 + rloc + r;
        float v = acc[i][j][r];
        if (j * 16 + 15 < H * 64) {
          xp[row * (H * 64) + col] = (f16)v;
        } else {
          if (col < H * 64) xp[row * (H * 64) + col] = (f16)v;
          else {
            int cc = col - H * 64;
            if (cc < 2 * H) {
              int hh = cc >> 1;
              if (cc & 1) ald[row * H + hh] = v; else als[row * H + hh] = v;
            }
          }
        }
      }
    }
  }
}

// ---------------- Mals[b][h] = max_n als[(b,n)][h] ----------------
template<int H>
__global__ __launch_bounds__(256) void k_maxals(const float* __restrict__ als, float* __restrict__ Mals) {
  __shared__ float red[256];
  int b = blockIdx.x, t = threadIdx.x;
  size_t rbase = (size_t)b << 12;
  for (int h = 0; h < H; ++h) {
    float m = -1e30f;
    for (int n = t; n < NN; n += 256) m = fmaxf(m, als[(rbase + n) * H + h]);
    red[t] = m;
    __syncthreads();
    for (int d = 128; d; d >>= 1) {
      if (t < d) red[t] = fmaxf(red[t], red[t + d]);
      __syncthreads();
    }
    if (t == 0) Mals[b * H + h] = red[0];
    __syncthreads();
  }
}

// ---------------- edge weights: w[b][p][h] = exp(leaky(als_src+ald_dst) - T) ----------------
// T = upper bound of ev over edges into dst: B = Mals[b][h] + ald[b][dst][h]; T = B>0 ? B : 0.2B.
// Softmax is shift-invariant, so any per-(b,dst,h) shift >= max works; this one needs no
// per-node max reduction and guarantees exp args <= 0 (no overflow).
template<int H>
__global__ __launch_bounds__(256) void k_wts(const float* __restrict__ als, const float* __restrict__ ald,
                                             const float* __restrict__ Mals, const int* __restrict__ esrc,
                                             const int* __restrict__ edst, float* __restrict__ wts) {
  int t = threadIdx.x, lane = t & 63, w = t >> 6;
  int gw = blockIdx.x * 4 + w;          // 9216 waves: 16 b x 576 p-groups
  int b = gw & 15;
  int p = ((gw >> 4) << 6) + lane;      // 64 consecutive CSR positions per wave
  size_t rbase = (size_t)b << 12;
  int s = esrc[p], n = edst[p];
  float* dst = wts + ((size_t)b * ETOT + p) * H;
  #pragma unroll
  for (int h = 0; h < H; ++h) {
    float ad = ald[(rbase + n) * H + h];
    float B = Mals[b * H + h] + ad;
    float T = B > 0.f ? B : 0.2f * B;
    float ev = als[(rbase + s) * H + h] + ad;
    ev = ev > 0.f ? ev : 0.2f * ev;
    dst[h] = __expf(ev - T);
  }
}

// ---------------- GAT aggregation: precomputed weights, no softmax machinery ----------------
template<int H>
__global__ __launch_bounds__(256) void k_agg(const f16* __restrict__ xp, const float* __restrict__ wts,
                                             const int* __restrict__ offs, const int* __restrict__ cnt,
                                             const int* __restrict__ esrc, const float* __restrict__ bg,
                                             float* __restrict__ hcur) {
  __shared__ float wbuf[4][H * 64];
  __shared__ int   sbuf[4][64];
  int t = threadIdx.x, lane = t & 63, wv = t >> 6;
  int wid = (blockIdx.x << 2) + wv;
  int b = wid >> 12, n = wid & 4095;
  size_t rbase = (size_t)b << 12;
  int o = offs[n], c = cnt[n];
  const float* wsrc = wts + ((size_t)b * ETOT + o) * H;
  float z[H], acc[H];
  #pragma unroll
  for (int hh = 0; hh < H; ++hh) { z[hh] = 0.f; acc[hh] = 0.f; }
  for (int e0 = 0; e0 < c; e0 += 64) {
    int ce = min(64, c - e0);
    if (lane < ce) {
      sbuf[wv][lane] = esrc[o + e0 + lane];
      #pragma unroll
      for (int hh = 0; hh < H; ++hh)
        wbuf[wv][hh * 64 + lane] = wsrc[(size_t)(e0 + lane) * H + hh];
    }
    for (int e = 0; e < ce; ++e) {
      int s = sbuf[wv][e];
      const f16* row = xp + (rbase + s) * (size_t)(H * 64) + lane;
      #pragma unroll
      for (int hh = 0; hh < H; ++hh) {
        float wv_ = wbuf[wv][hh * 64 + e];
        z[hh] += wv_;
        acc[hh] = fmaf(wv_, (float)row[hh << 6], acc[hh]);
      }
    }
  }
  float r = 0.f;
  #pragma unroll
  for (int hh = 0; hh < H; ++hh) r += acc[hh] / z[hh];
  hcur[(rbase + n) * 64 + lane] = r * (1.f / H) + bg[lane];
}

// ---------------- layer-0 combine (+ fused HT write); adp f16 partials * rowZ ----------------
__global__ __launch_bounds__(256) void k_comb0(const float* __restrict__ h, const f16* __restrict__ adp,
                                               const float* __restrict__ rowZ,
                                               const float* __restrict__ Wl, const float* __restrict__ bl,
                                               const float* __restrict__ Wo, const float* __restrict__ bo,
                                               float* __restrict__ hout, f16* __restrict__ HT) {
  __shared__ float Xa[64 * 68];
  __shared__ float Xh[64 * 68];
  int t = threadIdx.x;
  int b = blockIdx.x >> 6, n0 = (blockIdx.x & 63) << 6;
  #pragma unroll
  for (int i = 0; i < 4; ++i) {
    int idx = t + (i << 8);
    int nl = idx >> 4, d4 = (idx & 15) << 2;
    size_t arow = ((size_t)(n0 + nl) << 10) + (b << 6) + d4;
    float zi = rowZ[n0 + nl];
    float4 s = {0.f, 0.f, 0.f, 0.f};
    #pragma unroll
    for (int p = 0; p < KSPLIT; ++p) {
      f16x4 q = *(const f16x4*)&adp[arow + (size_t)p * (4096 * 1024)];
      s.x += (float)q[0]; s.y += (float)q[1]; s.z += (float)q[2]; s.w += (float)q[3];
    }
    s.x *= zi; s.y *= zi; s.z *= zi; s.w *= zi;
    *(float4*)&Xa[nl * 68 + d4] = s;
    *(float4*)&Xh[nl * 68 + d4] = *(const float4*)&h[((size_t)(b << 12) + n0 + nl) * 64 + d4];
  }
  __syncthreads();
  int c = t & 63, rg = t >> 6;
  float blc = bl[c], boc = bo[c];
  float Wc[64], gv[16], fv[16];
  #pragma unroll
  for (int k = 0; k < 64; ++k) Wc[k] = Wl[(k << 6) + c];
  for (int rr = 0; rr < 16; ++rr) {
    int r = (rg << 4) + rr;
    float ag = blc;
    #pragma unroll
    for (int k4 = 0; k4 < 16; ++k4) {
      float4 x = *(const float4*)&Xa[r * 68 + (k4 << 2)];
      ag = fmaf(x.x, Wc[4*k4+0], ag); ag = fmaf(x.y, Wc[4*k4+1], ag);
      ag = fmaf(x.z, Wc[4*k4+2], ag); ag = fmaf(x.w, Wc[4*k4+3], ag);
    }
    gv[rr] = 1.f / (1.f + __expf(-ag));
  }
  #pragma unroll
  for (int k = 0; k < 64; ++k) Wc[k] = Wo[(k << 6) + c];
  for (int rr = 0; rr < 16; ++rr) {
    int r = (rg << 4) + rr;
    float ao = boc;
    #pragma unroll
    for (int k4 = 0; k4 < 16; ++k4) {
      float4 x = *(const float4*)&Xh[r * 68 + (k4 << 2)];
      ao = fmaf(x.x, Wc[4*k4+0], ao); ao = fmaf(x.y, Wc[4*k4+1], ao);
      ao = fmaf(x.z, Wc[4*k4+2], ao); ao = fmaf(x.w, Wc[4*k4+3], ao);
    }
    float hv = Xh[r * 68 + c];
    float g = gv[rr];
    float val = tanhf(hv) * g + ao * (1.f - g);
    hout[((size_t)(b << 12) + n0 + r) * 64 + c] = val;
    fv[rr] = val;
  }
  __syncthreads();
  #pragma unroll
  for (int rr = 0; rr < 16; ++rr) Xh[((rg << 4) + rr) * 68 + c] = fv[rr];
  __syncthreads();
  int nl = t & 63, dg = t >> 6;
  #pragma unroll
  for (int i = 0; i < 16; ++i) {
    int d = (dg << 4) + i;
    HT[((size_t)((b << 6) + d) << 12) + n0 + nl] = (f16)Xh[nl * 68 + d];
  }
}

// ---------------- layer-1/2 combine (+ optional fused HT write); adp f16 partials * rowZ ----------------
template<int ACT, bool WRT>   // ACT 0: leaky 0.01, 1: relu
__global__ __launch_bounds__(256) void k_comb12(const float* __restrict__ h, const f16* __restrict__ adp,
                                                const float* __restrict__ rowZ,
                                                const float* __restrict__ hcur, const float* __restrict__ Wl,
                                                const float* __restrict__ bl, float* __restrict__ hout,
                                                f16* __restrict__ HT) {
  __shared__ float Xa[64 * 68];
  int t = threadIdx.x;
  int b = blockIdx.x >> 6, n0 = (blockIdx.x & 63) << 6;
  #pragma unroll
  for (int i = 0; i < 4; ++i) {
    int idx = t + (i << 8);
    int nl = idx >> 4, d4 = (idx & 15) << 2;
    size_t arow = ((size_t)(n0 + nl) << 10) + (b << 6) + d4;
    float zi = rowZ[n0 + nl];
    float4 s = {0.f, 0.f, 0.f, 0.f};
    #pragma unroll
    for (int p = 0; p < KSPLIT; ++p) {
      f16x4 q = *(const f16x4*)&adp[arow + (size_t)p * (4096 * 1024)];
      s.x += (float)q[0]; s.y += (float)q[1]; s.z += (float)q[2]; s.w += (float)q[3];
    }
    s.x *= zi; s.y *= zi; s.z *= zi; s.w *= zi;
    *(float4*)&Xa[nl * 68 + d4] = s;
  }
  __syncthreads();
  int c = t & 63, rg = t >> 6;
  float Wc[64];
  #pragma unroll
  for (int k = 0; k < 64; ++k) Wc[k] = Wl[(k << 6) + c];
  float blc = bl[c];
  float fv[16];
  for (int rr = 0; rr < 16; ++rr) {
    int r = (rg << 4) + rr;
    float ag = blc;
    #pragma unroll
    for (int k4 = 0; k4 < 16; ++k4) {
      float4 x = *(const float4*)&Xa[r * 68 + (k4 << 2)];
      ag = fmaf(x.x, Wc[4*k4+0], ag); ag = fmaf(x.y, Wc[4*k4+1], ag);
      ag = fmaf(x.z, Wc[4*k4+2], ag); ag = fmaf(x.w, Wc[4*k4+3], ag);
    }
    float g = 1.f / (1.f + __expf(-ag));
    size_t ridx = ((size_t)(b << 12) + n0 + r) * 64 + c;
    float hv = h[ridx], cv = hcur[ridx];
    float act = ACT ? fmaxf(cv, 0.f) : (cv > 0.f ? cv : 0.01f * cv);
    float val = act * g + hv * (1.f - g);
    hout[ridx] = val;
    fv[rr] = val;
  }
  if (WRT) {
    __syncthreads();
    #pragma unroll
    for (int rr = 0; rr < 16; ++rr) Xa[((rg << 4) + rr) * 68 + c] = fv[rr];
    __syncthreads();
    int nl = t & 63, dg = t >> 6;
    #pragma unroll
    for (int i = 0; i < 16; ++i) {
      int d = (dg << 4) + i;
      HT[((size_t)((b << 6) + d) << 12) + n0 + nl] = (f16)Xa[nl * 68 + d];
    }
  }
}

// ---------------- host launch ----------------
extern "C" void kernel_launch(void* const* d_in, const int* in_sizes, int n_in,
                              void* d_out, int out_size, void* d_ws, size_t ws_size,
                              hipStream_t stream) {
  (void)in_sizes; (void)n_in; (void)out_size; (void)ws_size;
  const float* inp  = (const float*)d_in[0];
  const int*   ei   = (const int*)d_in[1];
  const float* Wseq = (const float*)d_in[2];
  const float* bseq = (const float*)d_in[3];
  const float* SE   = (const float*)d_in[4];
  const float* TE   = (const float*)d_in[5];
  const float* Wg[3]   = {(const float*)d_in[6],  (const float*)d_in[12], (const float*)d_in[18]};
  const float* asrc[3] = {(const float*)d_in[7],  (const float*)d_in[13], (const float*)d_in[19]};
  const float* adst[3] = {(const float*)d_in[8],  (const float*)d_in[14], (const float*)d_in[20]};
  const float* bgp[3]  = {(const float*)d_in[9],  (const float*)d_in[15], (const float*)d_in[21]};
  const float* Wl[3]   = {(const float*)d_in[10], (const float*)d_in[16], (const float*)d_in[22]};
  const float* bl[3]   = {(const float*)d_in[11], (const float*)d_in[17], (const float*)d_in[23]};
  const float* Wo = (const float*)d_in[24];
  const float* bo = (const float*)d_in[25];
  float* out = (float*)d_out;

  uint8_t* ws = (uint8_t*)d_ws;
  size_t o = 0;
  auto nxt = [&](size_t sz) { void* p = ws + o; o += (sz + 255) & ~(size_t)255; return p; };
  f16*   Af   = (f16*)  nxt((size_t)NN * NN * sizeof(f16));        // 32 MB
  f16*   HT   = (f16*)  nxt((size_t)1024 * NN * sizeof(f16));      // 8 MB
  float* h    = (float*)nxt((size_t)ROWS * 64 * 4);                // 16 MB
  f16*   adp  = (f16*)  nxt((size_t)KSPLIT * NN * 1024 * sizeof(f16)); // 16 MB
  f16*   xp   = (f16*)  nxt((size_t)ROWS * 192 * sizeof(f16));     // 24 MB
  float* als  = (float*)nxt((size_t)ROWS * 3 * 4);
  float* ald  = (float*)nxt((size_t)ROWS * 3 * 4);
  float* hcur = (float*)nxt((size_t)ROWS * 64 * 4);                // 16 MB
  float* rowZ = (float*)nxt((size_t)NN * 4);
  float* Zpart= (float*)nxt((size_t)64 * NN * 4);                  // 1 MB
  f16*   SEh  = (f16*)  nxt((size_t)NN * 64 * sizeof(f16));
  f16*   TEh  = (f16*)  nxt((size_t)NN * 64 * sizeof(f16));
  f16*   Wgh  = (f16*)  nxt((size_t)256 * 64 * sizeof(f16));
  float* wts  = (float*)nxt((size_t)NB * ETOT * 3 * 4);            // 7.1 MB edge weights
  float* Mals = (float*)nxt((size_t)NB * 3 * 4);
  int*   cnt  = (int*)  nxt((size_t)NN * 4);
  int*   curp = (int*)  nxt((size_t)NN * 4);
  int*   offs = (int*)  nxt((size_t)NN * 4);
  int*   esrc = (int*)  nxt((size_t)ETOT * 4);
  int*   edst = (int*)  nxt((size_t)ETOT * 4);

  static bool attr_set = false;
  if (!attr_set) {
    hipFuncSetAttribute((const void*)k_gemm8, hipFuncAttributeMaxDynamicSharedMemorySize, 147456);
    attr_set = true;
  }

  dim3 blk(256);
  // CSR build
  k_zero<<<16, blk, 0, stream>>>(cnt, NN);
  k_zero<<<16, blk, 0, stream>>>(curp, NN);
  k_count<<<144, blk, 0, stream>>>(ei, cnt);
  k_scan<<<1, blk, 0, stream>>>(cnt, offs);
  k_fill<<<144, blk, 0, stream>>>(ei, offs, curp, esrc, edst);
  // h0 (+HT) + adjacency (MFMA path, raw exp + rowZ)
  k_seq<<<1024, blk, 0, stream>>>(inp, Wseq, bseq, h, HT);
  k_castSE<<<256, blk, 0, stream>>>(SE, SEh);
  k_castTE<<<64, blk, 0, stream>>>(TE, TEh);
  k_adjmm<<<dim3(32, 32), blk, 0, stream>>>(SEh, TEh, Af, Zpart);
  k_rowz<<<16, blk, 0, stream>>>(Zpart, rowZ);
  // ---- layer 0 ----
  k_gemm8<<<256, 512, 147456, stream>>>(Af, HT, adp);
  k_comb0<<<1024, blk, 0, stream>>>(h, adp, rowZ, Wl[0], bl[0], Wo, bo, h, HT);
  // ---- layer 1 ----
  k_wprep<3, 208><<<16, blk, 0, stream>>>(Wg[1], asrc[1], adst[1], Wgh);
  k_xpmm<3, 208><<<512, blk, 0, stream>>>(h, Wgh, xp, als, ald);
  k_maxals<3><<<16, blk, 0, stream>>>(als, Mals);
  k_wts<3><<<2304, blk, 0, stream>>>(als, ald, Mals, esrc, edst, wts);
  k_gemm8<<<256, 512, 147456, stream>>>(Af, HT, adp);
  k_agg<3><<<16384, blk, 0, stream>>>(xp, wts, offs, cnt, esrc, bgp[1], hcur);
  k_comb12<0, true><<<1024, blk, 0, stream>>>(h, adp, rowZ, hcur, Wl[1], bl[1], h, HT);
  // ---- layer 2 ----
  k_wprep<1, 80><<<16, blk, 0, stream>>>(Wg[2], asrc[2], adst[2], Wgh);
  k_xpmm<1, 80><<<512, blk, 0, stream>>>(h, Wgh, xp, als, ald);
  k_maxals<1><<<16, blk, 0, stream>>>(als, Mals);
  k_wts<1><<<2304, blk, 0, stream>>>(als, ald, Mals, esrc, edst, wts);
  k_gemm8<<<256, 512, 147456, stream>>>(Af, HT, adp);
  k_agg<1><<<16384, blk, 0, stream>>>(xp, wts, offs, cnt, esrc, bgp[2], hcur);
  k_comb12<1, false><<<1024, blk, 0, stream>>>(h, adp, rowZ, hcur, Wl[2], bl[2], out, (f16*)nullptr);
}

// Round 11
// 331.768 us; speedup vs baseline: 1.0911x; 1.0911x over previous
//
#include <hip/hip_runtime.h>
#include <stdint.h>

// ---- problem constants ----
#define NB 16        // batch
#define NN 4096      // nodes
#define DD 64        // feature dim (== S)
#define EE 32768     // edges (before self loops)
#define ETOT 36864   // edges + self loops
#define ROWS 65536   // B*N
#define KSPLIT 2

typedef _Float16 f16;
typedef f16   half8 __attribute__((ext_vector_type(8)));
typedef f16   f16x8 __attribute__((ext_vector_type(8)));
typedef f16   f16x4 __attribute__((ext_vector_type(4)));
typedef float f32x4 __attribute__((ext_vector_type(4)));

__device__ __forceinline__ void gload16(const f16* g, f16* l) {
  __builtin_amdgcn_global_load_lds((const __attribute__((address_space(1))) void*)g,
                                   (__attribute__((address_space(3))) void*)l, 16, 0, 0);
}

// ---------------- CSR build ----------------
__global__ __launch_bounds__(256) void k_zero(int* p, int n) {
  int i = blockIdx.x * 256 + threadIdx.x;
  if (i < n) p[i] = 0;
}

__global__ __launch_bounds__(256) void k_count(const int* __restrict__ ei, int* __restrict__ cnt) {
  int t = blockIdx.x * 256 + threadIdx.x;
  if (t >= ETOT) return;
  int d = (t < EE) ? ei[EE + t] : (t - EE);
  atomicAdd(&cnt[d], 1);
}

__global__ __launch_bounds__(256) void k_scan(const int* __restrict__ cnt, int* __restrict__ offs) {
  __shared__ int part[256];
  int t = threadIdx.x;
  int loc[16]; int s = 0;
  #pragma unroll
  for (int i = 0; i < 16; ++i) { int v = cnt[(t << 4) + i]; loc[i] = s; s += v; }
  part[t] = s;
  __syncthreads();
  int own = s;
  for (int d = 1; d < 256; d <<= 1) {
    int u = (t >= d) ? part[t - d] : 0;
    __syncthreads();
    part[t] += u;
    __syncthreads();
  }
  int base = part[t] - own;
  #pragma unroll
  for (int i = 0; i < 16; ++i) offs[(t << 4) + i] = base + loc[i];
}

__global__ __launch_bounds__(256) void k_fill(const int* __restrict__ ei, const int* __restrict__ offs,
                                              int* __restrict__ cur, int* __restrict__ esrc,
                                              int* __restrict__ edst) {
  int t = blockIdx.x * 256 + threadIdx.x;
  if (t >= ETOT) return;
  int s, d;
  if (t < EE) { s = ei[t]; d = ei[EE + t]; } else { s = d = t - EE; }
  int p = atomicAdd(&cur[d], 1);
  esrc[offs[d] + p] = s;
  edst[offs[d] + p] = d;
}

// ---------------- seq_linear: h = in^T @ Wseq + b + in^T ----------------
__global__ __launch_bounds__(256) void k_seq(const float* __restrict__ inp, const float* __restrict__ Wseq,
                                             const float* __restrict__ bseq, float* __restrict__ h) {
  __shared__ float X[64 * 68];
  int t = threadIdx.x;
  int b = blockIdx.x >> 6, n0 = (blockIdx.x & 63) << 6;
  #pragma unroll
  for (int i = 0; i < 16; ++i) {
    int idx = t + (i << 8);
    int s = idx >> 6, nl = idx & 63;
    X[nl * 68 + s] = inp[((size_t)((b << 6) + s) << 12) + n0 + nl];
  }
  __syncthreads();
  int c = t & 63, rg = t >> 6;
  float Wc[64];
  #pragma unroll
  for (int k = 0; k < 64; ++k) Wc[k] = Wseq[(k << 6) + c];
  float bc = bseq[c];
  for (int rr = 0; rr < 16; ++rr) {
    int r = (rg << 4) + rr;
    float a = bc + X[r * 68 + c];
    #pragma unroll
    for (int k4 = 0; k4 < 16; ++k4) {
      float4 x = *(const float4*)&X[r * 68 + (k4 << 2)];
      a = fmaf(x.x, Wc[4*k4+0], a); a = fmaf(x.y, Wc[4*k4+1], a);
      a = fmaf(x.z, Wc[4*k4+2], a); a = fmaf(x.w, Wc[4*k4+3], a);
    }
    h[((size_t)(b << 12) + n0 + r) * 64 + c] = a;
  }
}

// ---------------- adjacency prep: casts ----------------
__global__ __launch_bounds__(256) void k_castSE(const float* __restrict__ SE, f16* __restrict__ SEh) {
  int i = (blockIdx.x * 256 + threadIdx.x) * 4;
  float4 v = *(const float4*)(SE + i);
  f16 o[4] = {(f16)v.x, (f16)v.y, (f16)v.z, (f16)v.w};
  *(uint64_t*)(SEh + i) = *(uint64_t*)o;
}

__global__ __launch_bounds__(256) void k_castTE(const float* __restrict__ TE, f16* __restrict__ TEh) {
  __shared__ float X[64 * 65];
  int t = threadIdx.x;
  int j0 = blockIdx.x << 6;
  #pragma unroll
  for (int i = 0; i < 16; ++i) {
    int idx = t + (i << 8);           // 0..4095 = 64k x 64j
    int k = idx >> 6, jl = idx & 63;
    X[jl * 65 + k] = TE[((size_t)k << 12) + j0 + jl];
  }
  __syncthreads();
  int jl = t >> 2, kg = t & 3;        // 4 threads per output row, 16 k each
  f16 o[16];
  #pragma unroll
  for (int i = 0; i < 16; ++i) o[i] = (f16)X[jl * 65 + (kg << 4) + i];
  f16* dst = TEh + ((size_t)(j0 + jl) << 6) + (kg << 4);
  *(uint64_t*)(dst + 0) = *(uint64_t*)(o + 0);
  *(uint64_t*)(dst + 4) = *(uint64_t*)(o + 4);
  *(uint64_t*)(dst + 8) = *(uint64_t*)(o + 8);
  *(uint64_t*)(dst + 12) = *(uint64_t*)(o + 12);
}

// ---------------- adjacency MFMA GEMM: A = exp(relu(SEh @ TEh^T)) (raw), row partial sums ----------------
__global__ __launch_bounds__(256) void k_adjmm(const f16* __restrict__ SEh, const f16* __restrict__ TEh,
                                               f16* __restrict__ A, float* __restrict__ Zpart) {
  __shared__ f16 Al[128 * 32];
  __shared__ f16 Bl[128 * 32];
  const int t = threadIdx.x, lane = t & 63, w = t >> 6;
  const int m0 = blockIdx.y << 7, j0 = blockIdx.x << 7;
  const int l15 = lane & 15, lhi = lane >> 4;
  const int wm = (w >> 1) << 6, wj = (w & 1) << 6;
  f32x4 acc[4][4] = {};
  const int c0 = (w << 6) + lane;
  const int row0 = c0 >> 2, ko0 = (c0 & 3) << 3;
  const int c1 = c0 + 256;
  const int row1 = c1 >> 2, ko1 = (c1 & 3) << 3;
  const f16* ga0 = SEh + (size_t)(m0 + row0) * 64 + ko0;
  const f16* ga1 = SEh + (size_t)(m0 + row1) * 64 + ko1;
  const f16* gb0 = TEh + (size_t)(j0 + row0) * 64 + ko0;
  const f16* gb1 = TEh + (size_t)(j0 + row1) * 64 + ko1;
  f16* la0 = Al + c0 * 8; f16* la1 = Al + c1 * 8;
  f16* lb0 = Bl + c0 * 8; f16* lb1 = Bl + c1 * 8;
  for (int kt = 0; kt < 2; ++kt) {
    const int kof = kt << 5;
    gload16(ga0 + kof, la0);
    gload16(ga1 + kof, la1);
    gload16(gb0 + kof, lb0);
    gload16(gb1 + kof, lb1);
    __syncthreads();
    half8 af[4], bf[4];
    #pragma unroll
    for (int i = 0; i < 4; ++i) {
      af[i] = *(const half8*)(Al + (wm + i * 16 + l15) * 32 + lhi * 8);
      bf[i] = *(const half8*)(Bl + (wj + i * 16 + l15) * 32 + lhi * 8);
    }
    #pragma unroll
    for (int mi = 0; mi < 4; ++mi)
      #pragma unroll
      for (int nj = 0; nj < 4; ++nj)
        acc[mi][nj] = __builtin_amdgcn_mfma_f32_16x16x32_f16(af[mi], bf[nj], acc[mi][nj], 0, 0, 0);
    __syncthreads();
  }
  float rs[4][4];
  #pragma unroll
  for (int mi = 0; mi < 4; ++mi)
    #pragma unroll
    for (int r = 0; r < 4; ++r) rs[mi][r] = 0.f;
  #pragma unroll
  for (int mi = 0; mi < 4; ++mi)
    #pragma unroll
    for (int nj = 0; nj < 4; ++nj)
      #pragma unroll
      for (int r = 0; r < 4; ++r) {
        int row = m0 + wm + mi * 16 + lhi * 4 + r;
        int col = j0 + wj + nj * 16 + l15;
        float e = __expf(fmaxf(acc[mi][nj][r], 0.f));
        f16 eh = (f16)e;
        A[((size_t)row << 12) + col] = eh;
        rs[mi][r] += (float)eh;
      }
  #pragma unroll
  for (int mi = 0; mi < 4; ++mi)
    #pragma unroll
    for (int r = 0; r < 4; ++r) {
      float s = rs[mi][r];
      s += __shfl_xor(s, 1); s += __shfl_xor(s, 2);
      s += __shfl_xor(s, 4); s += __shfl_xor(s, 8);
      rs[mi][r] = s;
    }
  if (l15 == 0) {
    int p = (blockIdx.x << 1) + (w & 1);
    #pragma unroll
    for (int mi = 0; mi < 4; ++mi)
      #pragma unroll
      for (int r = 0; r < 4; ++r)
        Zpart[((size_t)p << 12) + m0 + wm + mi * 16 + lhi * 4 + r] = rs[mi][r];
  }
}

__global__ __launch_bounds__(256) void k_rowz(const float* __restrict__ Zpart, float* __restrict__ rowZ) {
  int row = blockIdx.x * 256 + threadIdx.x;
  float s = 0.f;
  #pragma unroll 8
  for (int p = 0; p < 64; ++p) s += Zpart[((size_t)p << 12) + row];
  rowZ[row] = 1.f / s;
}

// ---------------- big GEMM, 8-phase-style schedule (unchanged from R9) ----------------
#define NKT 32
__global__ __launch_bounds__(512) void k_gemm8(const f16* __restrict__ A, const f16* __restrict__ BT,
                                               f16* __restrict__ Cout) {
  extern __shared__ f16 smem[];
  const int t = threadIdx.x, lane = t & 63, wid = t >> 6;
  const int wr = wid >> 2, wc = wid & 3;
  const int l15 = lane & 15, lhi = lane >> 4;
  const int h7 = l15 & 7;
  const int wgid = blockIdx.x;
  const int nid = (wgid & 7) * 32 + (wgid >> 3);
  const int z = nid >> 7, rem = nid & 127;
  const int m0 = (rem >> 3) << 8;
  const int j0 = (rem & 7) << 7;
  const size_t kbase = (size_t)z << 11;
  f16* __restrict__ Cz = Cout + ((size_t)z << 22);

  const f16* gA[4]; int lA[4];
  #pragma unroll
  for (int i = 0; i < 4; ++i) {
    int s = t + (i << 9), row = s >> 3, sl = (s & 7) ^ (row & 7);
    gA[i] = A + (size_t)(m0 + row) * 4096 + kbase + sl * 8;
    lA[i] = s * 8;
  }
  const f16* gB[2]; int lB[2];
  #pragma unroll
  for (int i = 0; i < 2; ++i) {
    int s = t + (i << 9), row = s >> 3, sl = (s & 7) ^ (row & 7);
    gB[i] = BT + (size_t)(j0 + row) * 4096 + kbase + sl * 8;
    lB[i] = 16384 + s * 8;
  }
  #define SA(buf, kt, i) gload16(gA[i] + (kt) * 64, smem + (buf) * 24576 + lA[i])
  #define SB(buf, kt, i) gload16(gB[i] + (kt) * 64, smem + (buf) * 24576 + lB[i])

  const int rbase = wr << 7;
  const int cbase = wc << 5;
  f32x4 acc[8][2] = {};

  #pragma unroll
  for (int i = 0; i < 4; ++i) SA(0, 0, i);
  #pragma unroll
  for (int i = 0; i < 2; ++i) SB(0, 0, i);
  #pragma unroll
  for (int i = 0; i < 4; ++i) SA(1, 1, i);
  #pragma unroll
  for (int i = 0; i < 2; ++i) SB(1, 1, i);
  asm volatile("s_waitcnt vmcnt(6)" ::: "memory");
  __builtin_amdgcn_sched_barrier(0);
  __builtin_amdgcn_s_barrier();
  __builtin_amdgcn_sched_barrier(0);

  int b0 = 0, b1 = 1, b2 = 2;
  for (int kt = 0; kt < NKT; ++kt) {
    const f16* Ab = smem + b0 * 24576;
    const f16* Bb = Ab + 16384;
    const bool pf = (kt + 2 < NKT);
    {
      half8 af[8], bf[2];
      #pragma unroll
      for (int mi = 0; mi < 8; ++mi) {
        int row = rbase + mi * 16 + l15;
        af[mi] = *(const half8*)(Ab + row * 64 + (lhi ^ h7) * 8);
      }
      #pragma unroll
      for (int nj = 0; nj < 2; ++nj) {
        int row = cbase + nj * 16 + l15;
        bf[nj] = *(const half8*)(Bb + row * 64 + (lhi ^ h7) * 8);
      }
      if (pf) { SA(b2, kt + 2, 0); SA(b2, kt + 2, 1); SA(b2, kt + 2, 2); }
      __builtin_amdgcn_s_setprio(1);
      #pragma unroll
      for (int mi = 0; mi < 8; ++mi)
        #pragma unroll
        for (int nj = 0; nj < 2; ++nj)
          acc[mi][nj] = __builtin_amdgcn_mfma_f32_16x16x32_f16(af[mi], bf[nj], acc[mi][nj], 0, 0, 0);
      __builtin_amdgcn_s_setprio(0);
    }
    __builtin_amdgcn_s_barrier();
    __builtin_amdgcn_sched_barrier(0);
    {
      half8 af[8], bf[2];
      #pragma unroll
      for (int mi = 0; mi < 8; ++mi) {
        int row = rbase + mi * 16 + l15;
        af[mi] = *(const half8*)(Ab + row * 64 + ((4 + lhi) ^ h7) * 8);
      }
      #pragma unroll
      for (int nj = 0; nj < 2; ++nj) {
        int row = cbase + nj * 16 + l15;
        bf[nj] = *(const half8*)(Bb + row * 64 + ((4 + lhi) ^ h7) * 8);
      }
      if (pf) { SA(b2, kt + 2, 3); SB(b2, kt + 2, 0); SB(b2, kt + 2, 1); }
      __builtin_amdgcn_s_setprio(1);
      #pragma unroll
      for (int mi = 0; mi < 8; ++mi)
        #pragma unroll
        for (int nj = 0; nj < 2; ++nj)
          acc[mi][nj] = __builtin_amdgcn_mfma_f32_16x16x32_f16(af[mi], bf[nj], acc[mi][nj], 0, 0, 0);
      __builtin_amdgcn_s_setprio(0);
    }
    if (kt < NKT - 2)       asm volatile("s_waitcnt vmcnt(6)" ::: "memory");
    else if (kt == NKT - 2) asm volatile("s_waitcnt vmcnt(0)" ::: "memory");
    __builtin_amdgcn_sched_barrier(0);
    __builtin_amdgcn_s_barrier();
    __builtin_amdgcn_sched_barrier(0);
    int tb = b0; b0 = b1; b1 = b2; b2 = tb;
  }
  #undef SA
  #undef SB
  #pragma unroll
  for (int mi = 0; mi < 8; ++mi)
    #pragma unroll
    for (int nj = 0; nj < 2; ++nj)
      #pragma unroll
      for (int r = 0; r < 4; ++r) {
        int row = m0 + rbase + mi * 16 + (lhi << 2) + r;
        int col = j0 + cbase + nj * 16 + l15;
        Cz[(size_t)row * 1024 + col] = (f16)acc[mi][nj][r];
      }
}

// ---------------- Wgh prep: B^T cols = [Wg | va/vd | pad | Wl] ----------------
template<int H, int NP>
__global__ __launch_bounds__(256) void k_wprep(const float* __restrict__ Wg, const float* __restrict__ asrc,
                                               const float* __restrict__ adst, const float* __restrict__ Wl,
                                               f16* __restrict__ Wgh) {
  const int WL0 = H * 64 + 16;
  for (int i = blockIdx.x * 256 + threadIdx.x; i < NP * 64; i += 16 * 256) {
    int j = i >> 6, k = i & 63;
    float v;
    if (j < H * 64) {
      v = Wg[(size_t)k * (H * 64) + j];
    } else if (j < H * 64 + 2 * H) {
      int cc = j - H * 64, hh = cc >> 1;
      const float* a = ((cc & 1) ? adst : asrc) + (hh << 6);
      const float* wrow = Wg + (size_t)k * (H * 64) + (hh << 6);
      float s = 0.f;
      #pragma unroll 16
      for (int c = 0; c < 64; ++c) s = fmaf(wrow[c], a[c], s);
      v = s;
    } else if (j >= WL0 && j < WL0 + 64) {
      v = Wl[(k << 6) + (j - WL0)];
    } else v = 0.f;
    Wgh[(size_t)j * 64 + k] = (f16)v;
  }
}

// ---------------- W0h prep: [Wl0 | Wo] ----------------
__global__ __launch_bounds__(256) void k_w0prep(const float* __restrict__ Wl0, const float* __restrict__ Wo,
                                                f16* __restrict__ W0h) {
  for (int i = blockIdx.x * 256 + threadIdx.x; i < 128 * 64; i += 8 * 256) {
    int j = i >> 6, k = i & 63;
    float v = (j < 64) ? Wl0[(k << 6) + j] : Wo[(k << 6) + (j - 64)];
    W0h[(size_t)j * 64 + k] = (f16)v;
  }
}

// ---------------- xp = h @ Wg via MFMA + als/ald + HWlT (transposed gate projection) ----------------
// Block = 64 rows (consecutive n, one b). Cols: [0,H*64): xp; [H*64,H*64+2H): als/ald;
// [WL0, WL0+64): h@Wl -> staged in LDS -> transposed write HWlT[(b,e)][n].
template<int H, int NP>
__global__ __launch_bounds__(256) void k_xpmm(const float* __restrict__ h, const f16* __restrict__ Wgh,
                                              f16* __restrict__ xp, float* __restrict__ als,
                                              float* __restrict__ ald, f16* __restrict__ HWlT) {
  const int WL0 = H * 64 + 16, JW0 = WL0 / 16, NT = NP / 16;
  __shared__ f16 Ah[64 * 72];
  __shared__ f16 Bh[NP * 72];
  __shared__ f16 stage[64 * 72];     // [e][row]
  const int t = threadIdx.x, lane = t & 63, w = t >> 6;
  const size_t r0 = (size_t)blockIdx.x * 64;
  const int b = (int)(r0 >> 12), n0 = (int)(r0 & 4095);
  #pragma unroll
  for (int i = 0; i < 4; ++i) {
    int idx = t + (i << 8);
    int row = idx >> 4, k4 = (idx & 15) << 2;
    float4 v = *(const float4*)&h[(r0 + row) * 64 + k4];
    f16 o[4] = {(f16)v.x, (f16)v.y, (f16)v.z, (f16)v.w};
    *(uint64_t*)&Ah[row * 72 + k4] = *(uint64_t*)o;
  }
  for (int i = t; i < NP * 16; i += 256) {
    int row = i >> 4, k4 = (i & 15) << 2;
    *(uint64_t*)&Bh[row * 72 + k4] = *(const uint64_t*)&Wgh[(size_t)row * 64 + k4];
  }
  __syncthreads();
  const int l15 = lane & 15, lhi = lane >> 4;
  f32x4 acc[NT] = {};
  #pragma unroll
  for (int kk = 0; kk < 2; ++kk) {
    half8 af = *(const half8*)&Ah[(w * 16 + l15) * 72 + kk * 32 + lhi * 8];
    #pragma unroll
    for (int j = 0; j < NT; ++j) {
      half8 bf = *(const half8*)&Bh[(j * 16 + l15) * 72 + kk * 32 + lhi * 8];
      acc[j] = __builtin_amdgcn_mfma_f32_16x16x32_f16(af, bf, acc[j], 0, 0, 0);
    }
  }
  const int rl = w * 16 + lhi * 4;   // local row base for this thread's 4 outputs
  #pragma unroll
  for (int j = 0; j < NT; ++j) {
    int col = j * 16 + l15;
    if (j * 16 + 15 < H * 64) {                       // pure xp tile
      #pragma unroll
      for (int r = 0; r < 4; ++r)
        xp[(r0 + rl + r) * (H * 64) + col] = (f16)acc[j][r];
    } else if (j < JW0) {                             // va/vd tile (cols H*64 .. H*64+15)
      int cc = col - H * 64;
      if (cc >= 0 && cc < 2 * H) {
        int hh = cc >> 1;
        #pragma unroll
        for (int r = 0; r < 4; ++r) {
          if (cc & 1) ald[(r0 + rl + r) * H + hh] = acc[j][r];
          else        als[(r0 + rl + r) * H + hh] = acc[j][r];
        }
      }
    } else {                                          // Wl tile -> stage (e = col - WL0)
      int e = col - WL0;
      f16 o[4] = {(f16)acc[j][0], (f16)acc[j][1], (f16)acc[j][2], (f16)acc[j][3]};
      *(uint64_t*)&stage[e * 72 + rl] = *(uint64_t*)o;
    }
  }
  __syncthreads();
  {
    int e = t >> 2, seg = (t & 3) << 4;               // 64 e x 4 segs of 16 n
    float4 v0 = *(const float4*)&stage[e * 72 + seg];
    float4 v1 = *(const float4*)&stage[e * 72 + seg + 8];
    f16* dst = HWlT + (((size_t)((b << 6) + e)) << 12) + n0 + seg;
    *(float4*)dst = v0;
    *(float4*)(dst + 8) = v1;
  }
}

// ---------------- layer-0 prep: h @ [Wl0|Wo] -> HWlT (transposed) + orig (f16) ----------------
__global__ __launch_bounds__(256) void k_prep0(const float* __restrict__ h, const f16* __restrict__ W0h,
                                               f16* __restrict__ HWlT, f16* __restrict__ orig) {
  __shared__ f16 Ah[64 * 72];
  __shared__ f16 Bh[128 * 72];
  __shared__ f16 stage[64 * 72];
  const int t = threadIdx.x, lane = t & 63, w = t >> 6;
  const size_t r0 = (size_t)blockIdx.x * 64;
  const int b = (int)(r0 >> 12), n0 = (int)(r0 & 4095);
  #pragma unroll
  for (int i = 0; i < 4; ++i) {
    int idx = t + (i << 8);
    int row = idx >> 4, k4 = (idx & 15) << 2;
    float4 v = *(const float4*)&h[(r0 + row) * 64 + k4];
    f16 o[4] = {(f16)v.x, (f16)v.y, (f16)v.z, (f16)v.w};
    *(uint64_t*)&Ah[row * 72 + k4] = *(uint64_t*)o;
  }
  for (int i = t; i < 128 * 16; i += 256) {
    int row = i >> 4, k4 = (i & 15) << 2;
    *(uint64_t*)&Bh[row * 72 + k4] = *(const uint64_t*)&W0h[(size_t)row * 64 + k4];
  }
  __syncthreads();
  const int l15 = lane & 15, lhi = lane >> 4;
  f32x4 acc[8] = {};
  #pragma unroll
  for (int kk = 0; kk < 2; ++kk) {
    half8 af = *(const half8*)&Ah[(w * 16 + l15) * 72 + kk * 32 + lhi * 8];
    #pragma unroll
    for (int j = 0; j < 8; ++j) {
      half8 bf = *(const half8*)&Bh[(j * 16 + l15) * 72 + kk * 32 + lhi * 8];
      acc[j] = __builtin_amdgcn_mfma_f32_16x16x32_f16(af, bf, acc[j], 0, 0, 0);
    }
  }
  const int rl = w * 16 + lhi * 4;
  #pragma unroll
  for (int j = 0; j < 8; ++j) {
    int col = j * 16 + l15;
    if (j < 4) {                                      // Wl0 -> stage
      f16 o[4] = {(f16)acc[j][0], (f16)acc[j][1], (f16)acc[j][2], (f16)acc[j][3]};
      *(uint64_t*)&stage[col * 72 + rl] = *(uint64_t*)o;
    } else {                                          // Wo -> orig direct
      #pragma unroll
      for (int r = 0; r < 4; ++r)
        orig[(r0 + rl + r) * 64 + (col - 64)] = (f16)acc[j][r];
    }
  }
  __syncthreads();
  {
    int e = t >> 2, seg = (t & 3) << 4;
    float4 v0 = *(const float4*)&stage[e * 72 + seg];
    float4 v1 = *(const float4*)&stage[e * 72 + seg + 8];
    f16* dst = HWlT + (((size_t)((b << 6) + e)) << 12) + n0 + seg;
    *(float4*)dst = v0;
    *(float4*)(dst + 8) = v1;
  }
}

// ---------------- Mals[b][h] = max_n als[(b,n)][h] ----------------
template<int H>
__global__ __launch_bounds__(256) void k_maxals(const float* __restrict__ als, float* __restrict__ Mals) {
  __shared__ float red[256];
  int b = blockIdx.x, t = threadIdx.x;
  size_t rbase = (size_t)b << 12;
  for (int h = 0; h < H; ++h) {
    float m = -1e30f;
    for (int n = t; n < NN; n += 256) m = fmaxf(m, als[(rbase + n) * H + h]);
    red[t] = m;
    __syncthreads();
    for (int d = 128; d; d >>= 1) {
      if (t < d) red[t] = fmaxf(red[t], red[t + d]);
      __syncthreads();
    }
    if (t == 0) Mals[b * H + h] = red[0];
    __syncthreads();
  }
}

// ---------------- edge weights ----------------
template<int H>
__global__ __launch_bounds__(256) void k_wts(const float* __restrict__ als, const float* __restrict__ ald,
                                             const float* __restrict__ Mals, const int* __restrict__ esrc,
                                             const int* __restrict__ edst, float* __restrict__ wts) {
  int t = threadIdx.x, lane = t & 63, w = t >> 6;
  int gw = blockIdx.x * 4 + w;
  int b = gw & 15;
  int p = ((gw >> 4) << 6) + lane;
  size_t rbase = (size_t)b << 12;
  int s = esrc[p], n = edst[p];
  float* dst = wts + ((size_t)b * ETOT + p) * H;
  #pragma unroll
  for (int h = 0; h < H; ++h) {
    float ad = ald[(rbase + n) * H + h];
    float B = Mals[b * H + h] + ad;
    float T = B > 0.f ? B : 0.2f * B;
    float ev = als[(rbase + s) * H + h] + ad;
    ev = ev > 0.f ? ev : 0.2f * ev;
    dst[h] = __expf(ev - T);
  }
}

// ---------------- GAT aggregation: precomputed weights ----------------
template<int H>
__global__ __launch_bounds__(256) void k_agg(const f16* __restrict__ xp, const float* __restrict__ wts,
                                             const int* __restrict__ offs, const int* __restrict__ cnt,
                                             const int* __restrict__ esrc, const float* __restrict__ bg,
                                             float* __restrict__ hcur) {
  __shared__ float wbuf[4][H * 64];
  __shared__ int   sbuf[4][64];
  int t = threadIdx.x, lane = t & 63, wv = t >> 6;
  int wid = (blockIdx.x << 2) + wv;
  int b = wid >> 12, n = wid & 4095;
  size_t rbase = (size_t)b << 12;
  int o = offs[n], c = cnt[n];
  const float* wsrc = wts + ((size_t)b * ETOT + o) * H;
  float z[H], acc[H];
  #pragma unroll
  for (int hh = 0; hh < H; ++hh) { z[hh] = 0.f; acc[hh] = 0.f; }
  for (int e0 = 0; e0 < c; e0 += 64) {
    int ce = min(64, c - e0);
    if (lane < ce) {
      sbuf[wv][lane] = esrc[o + e0 + lane];
      #pragma unroll
      for (int hh = 0; hh < H; ++hh)
        wbuf[wv][hh * 64 + lane] = wsrc[(size_t)(e0 + lane) * H + hh];
    }
    for (int e = 0; e < ce; ++e) {
      int s = sbuf[wv][e];
      const f16* row = xp + (rbase + s) * (size_t)(H * 64) + lane;
      #pragma unroll
      for (int hh = 0; hh < H; ++hh) {
        float wv_ = wbuf[wv][hh * 64 + e];
        z[hh] += wv_;
        acc[hh] = fmaf(wv_, (float)row[hh << 6], acc[hh]);
      }
    }
  }
  float r = 0.f;
  #pragma unroll
  for (int hh = 0; hh < H; ++hh) r += acc[hh] / z[hh];
  hcur[(rbase + n) * 64 + lane] = r * (1.f / H) + bg[lane];
}

// ---------------- layer-0 combine: pure elementwise ----------------
__global__ __launch_bounds__(256) void k_comb0e(const float* __restrict__ h, const f16* __restrict__ gp,
                                                const float* __restrict__ rowZ, const f16* __restrict__ orig,
                                                const float* __restrict__ bl, const float* __restrict__ bo,
                                                float* __restrict__ hout) {
  for (size_t i4 = (size_t)blockIdx.x * 256 + threadIdx.x; i4 < (size_t)ROWS * 16; i4 += (size_t)2048 * 256) {
    size_t i = i4 * 4;
    int d = (int)(i & 63), n = (int)((i >> 6) & 4095), b = (int)(i >> 18);
    size_t ga = ((size_t)n << 10) + (b << 6) + d;
    float zi = rowZ[n];
    f16x4 g0 = *(const f16x4*)&gp[ga];
    f16x4 g1 = *(const f16x4*)&gp[ga + (size_t)(4096 * 1024)];
    f16x4 og = *(const f16x4*)&orig[i];
    float4 hv = *(const float4*)&h[i];
    float4 o;
    float* op = &o.x;
    const float* hp = &hv.x;
    #pragma unroll
    for (int r = 0; r < 4; ++r) {
      float g = 1.f / (1.f + __expf(-(((float)g0[r] + (float)g1[r]) * zi + bl[d + r])));
      float orv = (float)og[r] + bo[d + r];
      op[r] = tanhf(hp[r]) * g + orv * (1.f - g);
    }
    *(float4*)&hout[i] = o;
  }
}

// ---------------- layer-1/2 combine: pure elementwise ----------------
template<int ACT>   // 0: leaky 0.01, 1: relu
__global__ __launch_bounds__(256) void k_comb12e(const float* __restrict__ h, const f16* __restrict__ gp,
                                                 const float* __restrict__ rowZ, const float* __restrict__ hcur,
                                                 const float* __restrict__ bl, float* __restrict__ hout) {
  for (size_t i4 = (size_t)blockIdx.x * 256 + threadIdx.x; i4 < (size_t)ROWS * 16; i4 += (size_t)2048 * 256) {
    size_t i = i4 * 4;
    int d = (int)(i & 63), n = (int)((i >> 6) & 4095), b = (int)(i >> 18);
    size_t ga = ((size_t)n << 10) + (b << 6) + d;
    float zi = rowZ[n];
    f16x4 g0 = *(const f16x4*)&gp[ga];
    f16x4 g1 = *(const f16x4*)&gp[ga + (size_t)(4096 * 1024)];
    float4 hv = *(const float4*)&h[i];
    float4 cv = *(const float4*)&hcur[i];
    float4 o;
    float* op = &o.x;
    const float* hp = &hv.x;
    const float* cp = &cv.x;
    #pragma unroll
    for (int r = 0; r < 4; ++r) {
      float g = 1.f / (1.f + __expf(-(((float)g0[r] + (float)g1[r]) * zi + bl[d + r])));
      float act = ACT ? fmaxf(cp[r], 0.f) : (cp[r] > 0.f ? cp[r] : 0.01f * cp[r]);
      op[r] = act * g + hp[r] * (1.f - g);
    }
    *(float4*)&hout[i] = o;
  }
}

// ---------------- host launch ----------------
extern "C" void kernel_launch(void* const* d_in, const int* in_sizes, int n_in,
                              void* d_out, int out_size, void* d_ws, size_t ws_size,
                              hipStream_t stream) {
  (void)in_sizes; (void)n_in; (void)out_size; (void)ws_size;
  const float* inp  = (const float*)d_in[0];
  const int*   ei   = (const int*)d_in[1];
  const float* Wseq = (const float*)d_in[2];
  const float* bseq = (const float*)d_in[3];
  const float* SE   = (const float*)d_in[4];
  const float* TE   = (const float*)d_in[5];
  const float* Wg[3]   = {(const float*)d_in[6],  (const float*)d_in[12], (const float*)d_in[18]};
  const float* asrc[3] = {(const float*)d_in[7],  (const float*)d_in[13], (const float*)d_in[19]};
  const float* adst[3] = {(const float*)d_in[8],  (const float*)d_in[14], (const float*)d_in[20]};
  const float* bgp[3]  = {(const float*)d_in[9],  (const float*)d_in[15], (const float*)d_in[21]};
  const float* Wl[3]   = {(const float*)d_in[10], (const float*)d_in[16], (const float*)d_in[22]};
  const float* bl[3]   = {(const float*)d_in[11], (const float*)d_in[17], (const float*)d_in[23]};
  const float* Wo = (const float*)d_in[24];
  const float* bo = (const float*)d_in[25];
  float* out = (float*)d_out;

  uint8_t* ws = (uint8_t*)d_ws;
  size_t o = 0;
  auto nxt = [&](size_t sz) { void* p = ws + o; o += (sz + 255) & ~(size_t)255; return p; };
  f16*   Af   = (f16*)  nxt((size_t)NN * NN * sizeof(f16));        // 32 MB
  f16*   HWlT = (f16*)  nxt((size_t)1024 * NN * sizeof(f16));      // 8 MB (B operand, transposed proj)
  float* h    = (float*)nxt((size_t)ROWS * 64 * 4);                // 16 MB
  f16*   gp   = (f16*)  nxt((size_t)KSPLIT * NN * 1024 * sizeof(f16)); // 16 MB gate-pre partials
  f16*   xp   = (f16*)  nxt((size_t)ROWS * 192 * sizeof(f16));     // 24 MB
  f16*   orig = (f16*)  nxt((size_t)ROWS * 64 * sizeof(f16));      // 8 MB
  float* als  = (float*)nxt((size_t)ROWS * 3 * 4);
  float* ald  = (float*)nxt((size_t)ROWS * 3 * 4);
  float* hcur = (float*)nxt((size_t)ROWS * 64 * 4);                // 16 MB
  float* rowZ = (float*)nxt((size_t)NN * 4);
  float* Zpart= (float*)nxt((size_t)64 * NN * 4);                  // 1 MB
  f16*   SEh  = (f16*)  nxt((size_t)NN * 64 * sizeof(f16));
  f16*   TEh  = (f16*)  nxt((size_t)NN * 64 * sizeof(f16));
  f16*   Wgh  = (f16*)  nxt((size_t)288 * 64 * sizeof(f16));
  f16*   W0h  = (f16*)  nxt((size_t)128 * 64 * sizeof(f16));
  float* wts  = (float*)nxt((size_t)NB * ETOT * 3 * 4);            // 7.1 MB
  float* Mals = (float*)nxt((size_t)NB * 3 * 4);
  int*   cnt  = (int*)  nxt((size_t)NN * 4);
  int*   curp = (int*)  nxt((size_t)NN * 4);
  int*   offs = (int*)  nxt((size_t)NN * 4);
  int*   esrc = (int*)  nxt((size_t)ETOT * 4);
  int*   edst = (int*)  nxt((size_t)ETOT * 4);

  static bool attr_set = false;
  if (!attr_set) {
    hipFuncSetAttribute((const void*)k_gemm8, hipFuncAttributeMaxDynamicSharedMemorySize, 147456);
    attr_set = true;
  }

  dim3 blk(256);
  // CSR build
  k_zero<<<16, blk, 0, stream>>>(cnt, NN);
  k_zero<<<16, blk, 0, stream>>>(curp, NN);
  k_count<<<144, blk, 0, stream>>>(ei, cnt);
  k_scan<<<1, blk, 0, stream>>>(cnt, offs);
  k_fill<<<144, blk, 0, stream>>>(ei, offs, curp, esrc, edst);
  // h0 + adjacency
  k_seq<<<1024, blk, 0, stream>>>(inp, Wseq, bseq, h);
  k_castSE<<<256, blk, 0, stream>>>(SE, SEh);
  k_castTE<<<64, blk, 0, stream>>>(TE, TEh);
  k_adjmm<<<dim3(32, 32), blk, 0, stream>>>(SEh, TEh, Af, Zpart);
  k_rowz<<<16, blk, 0, stream>>>(Zpart, rowZ);
  // ---- layer 0 ----
  k_w0prep<<<8, blk, 0, stream>>>(Wl[0], Wo, W0h);
  k_prep0<<<1024, blk, 0, stream>>>(h, W0h, HWlT, orig);
  k_gemm8<<<256, 512, 147456, stream>>>(Af, HWlT, gp);
  k_comb0e<<<2048, blk, 0, stream>>>(h, gp, rowZ, orig, bl[0], bo, h);
  // ---- layer 1 ----
  k_wprep<3, 272><<<16, blk, 0, stream>>>(Wg[1], asrc[1], adst[1], Wl[1], Wgh);
  k_xpmm<3, 272><<<1024, blk, 0, stream>>>(h, Wgh, xp, als, ald, HWlT);
  k_maxals<3><<<16, blk, 0, stream>>>(als, Mals);
  k_wts<3><<<2304, blk, 0, stream>>>(als, ald, Mals, esrc, edst, wts);
  k_gemm8<<<256, 512, 147456, stream>>>(Af, HWlT, gp);
  k_agg<3><<<16384, blk, 0, stream>>>(xp, wts, offs, cnt, esrc, bgp[1], hcur);
  k_comb12e<0><<<2048, blk, 0, stream>>>(h, gp, rowZ, hcur, bl[1], h);
  // ---- layer 2 ----
  k_wprep<1, 144><<<16, blk, 0, stream>>>(Wg[2], asrc[2], adst[2], Wl[2], Wgh);
  k_xpmm<1, 144><<<1024, blk, 0, stream>>>(h, Wgh, xp, als, ald, HWlT);
  k_maxals<1><<<16, blk, 0, stream>>>(als, Mals);
  k_wts<1><<<2304, blk, 0, stream>>>(als, ald, Mals, esrc, edst, wts);
  k_gemm8<<<256, 512, 147456, stream>>>(Af, HWlT, gp);
  k_agg<1><<<16384, blk, 0, stream>>>(xp, wts, offs, cnt, esrc, bgp[2], hcur);
  k_comb12e<1><<<2048, blk, 0, stream>>>(h, gp, rowZ, hcur, bl[2], out);
}

// Round 12
// 328.433 us; speedup vs baseline: 1.1022x; 1.0102x over previous
//
#include <hip/hip_runtime.h>
#include <stdint.h>

// ---- problem constants ----
#define NB 16        // batch
#define NN 4096      // nodes
#define DD 64        // feature dim (== S)
#define EE 32768     // edges (before self loops)
#define ETOT 36864   // edges + self loops
#define ROWS 65536   // B*N
#define KSPLIT 2

typedef _Float16 f16;
typedef f16   half8 __attribute__((ext_vector_type(8)));
typedef f16   f16x8 __attribute__((ext_vector_type(8)));
typedef f16   f16x4 __attribute__((ext_vector_type(4)));
typedef float f32x4 __attribute__((ext_vector_type(4)));

__device__ __forceinline__ void gload16(const f16* g, f16* l) {
  __builtin_amdgcn_global_load_lds((const __attribute__((address_space(1))) void*)g,
                                   (__attribute__((address_space(3))) void*)l, 16, 0, 0);
}

// ---------------- CSR build ----------------
__global__ __launch_bounds__(256) void k_zero2(int* a, int* b) {
  int i = blockIdx.x * 256 + threadIdx.x;
  if (i < NN) a[i] = 0;
  else if (i < 2 * NN) b[i - NN] = 0;
}

__global__ __launch_bounds__(256) void k_count(const int* __restrict__ ei, int* __restrict__ cnt) {
  int t = blockIdx.x * 256 + threadIdx.x;
  if (t >= ETOT) return;
  int d = (t < EE) ? ei[EE + t] : (t - EE);
  atomicAdd(&cnt[d], 1);
}

__global__ __launch_bounds__(256) void k_scan(const int* __restrict__ cnt, int* __restrict__ offs) {
  __shared__ int part[256];
  int t = threadIdx.x;
  int loc[16]; int s = 0;
  #pragma unroll
  for (int i = 0; i < 16; ++i) { int v = cnt[(t << 4) + i]; loc[i] = s; s += v; }
  part[t] = s;
  __syncthreads();
  int own = s;
  for (int d = 1; d < 256; d <<= 1) {
    int u = (t >= d) ? part[t - d] : 0;
    __syncthreads();
    part[t] += u;
    __syncthreads();
  }
  int base = part[t] - own;
  #pragma unroll
  for (int i = 0; i < 16; ++i) offs[(t << 4) + i] = base + loc[i];
}

__global__ __launch_bounds__(256) void k_fill(const int* __restrict__ ei, const int* __restrict__ offs,
                                              int* __restrict__ cur, int* __restrict__ esrc,
                                              int* __restrict__ edst) {
  int t = blockIdx.x * 256 + threadIdx.x;
  if (t >= ETOT) return;
  int s, d;
  if (t < EE) { s = ei[t]; d = ei[EE + t]; } else { s = d = t - EE; }
  int p = atomicAdd(&cur[d], 1);
  esrc[offs[d] + p] = s;
  edst[offs[d] + p] = d;
}

// ---------------- seq_linear: h = in^T @ Wseq + b + in^T ----------------
__global__ __launch_bounds__(256) void k_seq(const float* __restrict__ inp, const float* __restrict__ Wseq,
                                             const float* __restrict__ bseq, float* __restrict__ h) {
  __shared__ float X[64 * 68];
  int t = threadIdx.x;
  int b = blockIdx.x >> 6, n0 = (blockIdx.x & 63) << 6;
  #pragma unroll
  for (int i = 0; i < 16; ++i) {
    int idx = t + (i << 8);
    int s = idx >> 6, nl = idx & 63;
    X[nl * 68 + s] = inp[((size_t)((b << 6) + s) << 12) + n0 + nl];
  }
  __syncthreads();
  int c = t & 63, rg = t >> 6;
  float Wc[64];
  #pragma unroll
  for (int k = 0; k < 64; ++k) Wc[k] = Wseq[(k << 6) + c];
  float bc = bseq[c];
  for (int rr = 0; rr < 16; ++rr) {
    int r = (rg << 4) + rr;
    float a = bc + X[r * 68 + c];
    #pragma unroll
    for (int k4 = 0; k4 < 16; ++k4) {
      float4 x = *(const float4*)&X[r * 68 + (k4 << 2)];
      a = fmaf(x.x, Wc[4*k4+0], a); a = fmaf(x.y, Wc[4*k4+1], a);
      a = fmaf(x.z, Wc[4*k4+2], a); a = fmaf(x.w, Wc[4*k4+3], a);
    }
    h[((size_t)(b << 12) + n0 + r) * 64 + c] = a;
  }
}

// ---------------- fused casts: blocks 0..255 SE, 256..319 TE ----------------
__global__ __launch_bounds__(256) void k_cast(const float* __restrict__ SE, const float* __restrict__ TE,
                                              f16* __restrict__ SEh, f16* __restrict__ TEh) {
  __shared__ float X[64 * 65];
  int t = threadIdx.x;
  if (blockIdx.x < 256) {
    int i = (blockIdx.x * 256 + t) * 4;
    float4 v = *(const float4*)(SE + i);
    f16 o[4] = {(f16)v.x, (f16)v.y, (f16)v.z, (f16)v.w};
    *(uint64_t*)(SEh + i) = *(uint64_t*)o;
    return;
  }
  int j0 = (blockIdx.x - 256) << 6;
  #pragma unroll
  for (int i = 0; i < 16; ++i) {
    int idx = t + (i << 8);
    int k = idx >> 6, jl = idx & 63;
    X[jl * 65 + k] = TE[((size_t)k << 12) + j0 + jl];
  }
  __syncthreads();
  int jl = t >> 2, kg = t & 3;
  f16 o[16];
  #pragma unroll
  for (int i = 0; i < 16; ++i) o[i] = (f16)X[jl * 65 + (kg << 4) + i];
  f16* dst = TEh + ((size_t)(j0 + jl) << 6) + (kg << 4);
  *(uint64_t*)(dst + 0) = *(uint64_t*)(o + 0);
  *(uint64_t*)(dst + 4) = *(uint64_t*)(o + 4);
  *(uint64_t*)(dst + 8) = *(uint64_t*)(o + 8);
  *(uint64_t*)(dst + 12) = *(uint64_t*)(o + 12);
}

// ---------------- adjacency MFMA GEMM: single-stage (one barrier), exp(relu) epilogue ----------------
__global__ __launch_bounds__(256) void k_adjmm(const f16* __restrict__ SEh, const f16* __restrict__ TEh,
                                               f16* __restrict__ A, float* __restrict__ Zpart) {
  __shared__ f16 Al[2][128 * 32];
  __shared__ f16 Bl[2][128 * 32];
  const int t = threadIdx.x, lane = t & 63, w = t >> 6;
  const int m0 = blockIdx.y << 7, j0 = blockIdx.x << 7;
  const int l15 = lane & 15, lhi = lane >> 4;
  const int wm = (w >> 1) << 6, wj = (w & 1) << 6;
  f32x4 acc[4][4] = {};
  const int c0 = (w << 6) + lane;
  const int row0 = c0 >> 2, ko0 = (c0 & 3) << 3;
  const int c1 = c0 + 256;
  const int row1 = c1 >> 2, ko1 = (c1 & 3) << 3;
  const f16* ga0 = SEh + (size_t)(m0 + row0) * 64 + ko0;
  const f16* ga1 = SEh + (size_t)(m0 + row1) * 64 + ko1;
  const f16* gb0 = TEh + (size_t)(j0 + row0) * 64 + ko0;
  const f16* gb1 = TEh + (size_t)(j0 + row1) * 64 + ko1;
  #pragma unroll
  for (int kt = 0; kt < 2; ++kt) {
    const int kof = kt << 5;
    gload16(ga0 + kof, Al[kt] + c0 * 8);
    gload16(ga1 + kof, Al[kt] + c1 * 8);
    gload16(gb0 + kof, Bl[kt] + c0 * 8);
    gload16(gb1 + kof, Bl[kt] + c1 * 8);
  }
  __syncthreads();
  #pragma unroll
  for (int kt = 0; kt < 2; ++kt) {
    half8 af[4], bf[4];
    #pragma unroll
    for (int i = 0; i < 4; ++i) {
      af[i] = *(const half8*)(Al[kt] + (wm + i * 16 + l15) * 32 + lhi * 8);
      bf[i] = *(const half8*)(Bl[kt] + (wj + i * 16 + l15) * 32 + lhi * 8);
    }
    #pragma unroll
    for (int mi = 0; mi < 4; ++mi)
      #pragma unroll
      for (int nj = 0; nj < 4; ++nj)
        acc[mi][nj] = __builtin_amdgcn_mfma_f32_16x16x32_f16(af[mi], bf[nj], acc[mi][nj], 0, 0, 0);
  }
  float rs[4][4];
  #pragma unroll
  for (int mi = 0; mi < 4; ++mi)
    #pragma unroll
    for (int r = 0; r < 4; ++r) rs[mi][r] = 0.f;
  #pragma unroll
  for (int mi = 0; mi < 4; ++mi)
    #pragma unroll
    for (int nj = 0; nj < 4; ++nj)
      #pragma unroll
      for (int r = 0; r < 4; ++r) {
        int row = m0 + wm + mi * 16 + lhi * 4 + r;
        int col = j0 + wj + nj * 16 + l15;
        float e = __expf(fmaxf(acc[mi][nj][r], 0.f));
        f16 eh = (f16)e;
        A[((size_t)row << 12) + col] = eh;
        rs[mi][r] += (float)eh;
      }
  #pragma unroll
  for (int mi = 0; mi < 4; ++mi)
    #pragma unroll
    for (int r = 0; r < 4; ++r) {
      float s = rs[mi][r];
      s += __shfl_xor(s, 1); s += __shfl_xor(s, 2);
      s += __shfl_xor(s, 4); s += __shfl_xor(s, 8);
      rs[mi][r] = s;
    }
  if (l15 == 0) {
    int p = (blockIdx.x << 1) + (w & 1);
    #pragma unroll
    for (int mi = 0; mi < 4; ++mi)
      #pragma unroll
      for (int r = 0; r < 4; ++r)
        Zpart[((size_t)p << 12) + m0 + wm + mi * 16 + lhi * 4 + r] = rs[mi][r];
  }
}

__global__ __launch_bounds__(256) void k_rowz(const float* __restrict__ Zpart, float* __restrict__ rowZ) {
  int row = blockIdx.x * 256 + threadIdx.x;
  float s = 0.f;
  #pragma unroll 8
  for (int p = 0; p < 64; ++p) s += Zpart[((size_t)p << 12) + row];
  rowZ[row] = 1.f / s;
}

// ---------------- big GEMM, 8-phase-style schedule (unchanged) ----------------
#define NKT 32
__global__ __launch_bounds__(512) void k_gemm8(const f16* __restrict__ A, const f16* __restrict__ BT,
                                               f16* __restrict__ Cout) {
  extern __shared__ f16 smem[];
  const int t = threadIdx.x, lane = t & 63, wid = t >> 6;
  const int wr = wid >> 2, wc = wid & 3;
  const int l15 = lane & 15, lhi = lane >> 4;
  const int h7 = l15 & 7;
  const int wgid = blockIdx.x;
  const int nid = (wgid & 7) * 32 + (wgid >> 3);
  const int z = nid >> 7, rem = nid & 127;
  const int m0 = (rem >> 3) << 8;
  const int j0 = (rem & 7) << 7;
  const size_t kbase = (size_t)z << 11;
  f16* __restrict__ Cz = Cout + ((size_t)z << 22);

  const f16* gA[4]; int lA[4];
  #pragma unroll
  for (int i = 0; i < 4; ++i) {
    int s = t + (i << 9), row = s >> 3, sl = (s & 7) ^ (row & 7);
    gA[i] = A + (size_t)(m0 + row) * 4096 + kbase + sl * 8;
    lA[i] = s * 8;
  }
  const f16* gB[2]; int lB[2];
  #pragma unroll
  for (int i = 0; i < 2; ++i) {
    int s = t + (i << 9), row = s >> 3, sl = (s & 7) ^ (row & 7);
    gB[i] = BT + (size_t)(j0 + row) * 4096 + kbase + sl * 8;
    lB[i] = 16384 + s * 8;
  }
  #define SA(buf, kt, i) gload16(gA[i] + (kt) * 64, smem + (buf) * 24576 + lA[i])
  #define SB(buf, kt, i) gload16(gB[i] + (kt) * 64, smem + (buf) * 24576 + lB[i])

  const int rbase = wr << 7;
  const int cbase = wc << 5;
  f32x4 acc[8][2] = {};

  #pragma unroll
  for (int i = 0; i < 4; ++i) SA(0, 0, i);
  #pragma unroll
  for (int i = 0; i < 2; ++i) SB(0, 0, i);
  #pragma unroll
  for (int i = 0; i < 4; ++i) SA(1, 1, i);
  #pragma unroll
  for (int i = 0; i < 2; ++i) SB(1, 1, i);
  asm volatile("s_waitcnt vmcnt(6)" ::: "memory");
  __builtin_amdgcn_sched_barrier(0);
  __builtin_amdgcn_s_barrier();
  __builtin_amdgcn_sched_barrier(0);

  int b0 = 0, b1 = 1, b2 = 2;
  for (int kt = 0; kt < NKT; ++kt) {
    const f16* Ab = smem + b0 * 24576;
    const f16* Bb = Ab + 16384;
    const bool pf = (kt + 2 < NKT);
    {
      half8 af[8], bf[2];
      #pragma unroll
      for (int mi = 0; mi < 8; ++mi) {
        int row = rbase + mi * 16 + l15;
        af[mi] = *(const half8*)(Ab + row * 64 + (lhi ^ h7) * 8);
      }
      #pragma unroll
      for (int nj = 0; nj < 2; ++nj) {
        int row = cbase + nj * 16 + l15;
        bf[nj] = *(const half8*)(Bb + row * 64 + (lhi ^ h7) * 8);
      }
      if (pf) { SA(b2, kt + 2, 0); SA(b2, kt + 2, 1); SA(b2, kt + 2, 2); }
      __builtin_amdgcn_s_setprio(1);
      #pragma unroll
      for (int mi = 0; mi < 8; ++mi)
        #pragma unroll
        for (int nj = 0; nj < 2; ++nj)
          acc[mi][nj] = __builtin_amdgcn_mfma_f32_16x16x32_f16(af[mi], bf[nj], acc[mi][nj], 0, 0, 0);
      __builtin_amdgcn_s_setprio(0);
    }
    __builtin_amdgcn_s_barrier();
    __builtin_amdgcn_sched_barrier(0);
    {
      half8 af[8], bf[2];
      #pragma unroll
      for (int mi = 0; mi < 8; ++mi) {
        int row = rbase + mi * 16 + l15;
        af[mi] = *(const half8*)(Ab + row * 64 + ((4 + lhi) ^ h7) * 8);
      }
      #pragma unroll
      for (int nj = 0; nj < 2; ++nj) {
        int row = cbase + nj * 16 + l15;
        bf[nj] = *(const half8*)(Bb + row * 64 + ((4 + lhi) ^ h7) * 8);
      }
      if (pf) { SA(b2, kt + 2, 3); SB(b2, kt + 2, 0); SB(b2, kt + 2, 1); }
      __builtin_amdgcn_s_setprio(1);
      #pragma unroll
      for (int mi = 0; mi < 8; ++mi)
        #pragma unroll
        for (int nj = 0; nj < 2; ++nj)
          acc[mi][nj] = __builtin_amdgcn_mfma_f32_16x16x32_f16(af[mi], bf[nj], acc[mi][nj], 0, 0, 0);
      __builtin_amdgcn_s_setprio(0);
    }
    if (kt < NKT - 2)       asm volatile("s_waitcnt vmcnt(6)" ::: "memory");
    else if (kt == NKT - 2) asm volatile("s_waitcnt vmcnt(0)" ::: "memory");
    __builtin_amdgcn_sched_barrier(0);
    __builtin_amdgcn_s_barrier();
    __builtin_amdgcn_sched_barrier(0);
    int tb = b0; b0 = b1; b1 = b2; b2 = tb;
  }
  #undef SA
  #undef SB
  #pragma unroll
  for (int mi = 0; mi < 8; ++mi)
    #pragma unroll
    for (int nj = 0; nj < 2; ++nj)
      #pragma unroll
      for (int r = 0; r < 4; ++r) {
        int row = m0 + rbase + mi * 16 + (lhi << 2) + r;
        int col = j0 + cbase + nj * 16 + l15;
        Cz[(size_t)row * 1024 + col] = (f16)acc[mi][nj][r];
      }
}

// ---------------- fused weight prep: Wgh1, Wgh2, W0h in one launch ----------------
template<int H, int NP>
__device__ __forceinline__ void wprep_body(const float* __restrict__ Wg, const float* __restrict__ asrc,
                                           const float* __restrict__ adst, const float* __restrict__ Wl,
                                           f16* __restrict__ Wgh, int bid, int t) {
  const int WL0 = H * 64 + 16;
  for (int i = bid * 256 + t; i < NP * 64; i += 16 * 256) {
    int j = i >> 6, k = i & 63;
    float v;
    if (j < H * 64) {
      v = Wg[(size_t)k * (H * 64) + j];
    } else if (j < H * 64 + 2 * H) {
      int cc = j - H * 64, hh = cc >> 1;
      const float* a = ((cc & 1) ? adst : asrc) + (hh << 6);
      const float* wrow = Wg + (size_t)k * (H * 64) + (hh << 6);
      float s = 0.f;
      #pragma unroll 16
      for (int c = 0; c < 64; ++c) s = fmaf(wrow[c], a[c], s);
      v = s;
    } else if (j >= WL0 && j < WL0 + 64) {
      v = Wl[(k << 6) + (j - WL0)];
    } else v = 0.f;
    Wgh[(size_t)j * 64 + k] = (f16)v;
  }
}

__global__ __launch_bounds__(256) void k_allprep(
    const float* __restrict__ Wg1, const float* __restrict__ as1, const float* __restrict__ ad1,
    const float* __restrict__ Wl1, f16* __restrict__ Wgh1,
    const float* __restrict__ Wg2, const float* __restrict__ as2, const float* __restrict__ ad2,
    const float* __restrict__ Wl2, f16* __restrict__ Wgh2,
    const float* __restrict__ Wl0, const float* __restrict__ Wo, f16* __restrict__ W0h) {
  int bid = blockIdx.x, t = threadIdx.x;
  if (bid < 16) wprep_body<3, 272>(Wg1, as1, ad1, Wl1, Wgh1, bid, t);
  else if (bid < 32) wprep_body<1, 144>(Wg2, as2, ad2, Wl2, Wgh2, bid - 16, t);
  else {
    for (int i = (bid - 32) * 256 + t; i < 128 * 64; i += 8 * 256) {
      int j = i >> 6, k = i & 63;
      float v = (j < 64) ? Wl0[(k << 6) + j] : Wo[(k << 6) + (j - 64)];
      W0h[(size_t)j * 64 + k] = (f16)v;
    }
  }
}

// ---------------- xp = h @ Wg via MFMA + als/ald + HWlT ----------------
// H==3: xp stored head-interleaved [row][d][4] (f16x4/lane in k_agg). H==1: [row][64].
template<int H, int NP>
__global__ __launch_bounds__(256) void k_xpmm(const float* __restrict__ h, const f16* __restrict__ Wgh,
                                              f16* __restrict__ xp, float* __restrict__ als,
                                              float* __restrict__ ald, f16* __restrict__ HWlT) {
  const int WL0 = H * 64 + 16, JW0 = WL0 / 16, NT = NP / 16;
  __shared__ f16 Ah[64 * 72];
  __shared__ f16 Bh[NP * 72];
  __shared__ f16 stage[64 * 72];
  const int t = threadIdx.x, lane = t & 63, w = t >> 6;
  const size_t r0 = (size_t)blockIdx.x * 64;
  const int b = (int)(r0 >> 12), n0 = (int)(r0 & 4095);
  #pragma unroll
  for (int i = 0; i < 4; ++i) {
    int idx = t + (i << 8);
    int row = idx >> 4, k4 = (idx & 15) << 2;
    float4 v = *(const float4*)&h[(r0 + row) * 64 + k4];
    f16 o[4] = {(f16)v.x, (f16)v.y, (f16)v.z, (f16)v.w};
    *(uint64_t*)&Ah[row * 72 + k4] = *(uint64_t*)o;
  }
  for (int i = t; i < NP * 16; i += 256) {
    int row = i >> 4, k4 = (i & 15) << 2;
    *(uint64_t*)&Bh[row * 72 + k4] = *(const uint64_t*)&Wgh[(size_t)row * 64 + k4];
  }
  __syncthreads();
  const int l15 = lane & 15, lhi = lane >> 4;
  f32x4 acc[NT] = {};
  #pragma unroll
  for (int kk = 0; kk < 2; ++kk) {
    half8 af = *(const half8*)&Ah[(w * 16 + l15) * 72 + kk * 32 + lhi * 8];
    #pragma unroll
    for (int j = 0; j < NT; ++j) {
      half8 bf = *(const half8*)&Bh[(j * 16 + l15) * 72 + kk * 32 + lhi * 8];
      acc[j] = __builtin_amdgcn_mfma_f32_16x16x32_f16(af, bf, acc[j], 0, 0, 0);
    }
  }
  const int rl = w * 16 + lhi * 4;
  #pragma unroll
  for (int j = 0; j < NT; ++j) {
    int col = j * 16 + l15;
    if (j * 16 + 15 < H * 64) {
      #pragma unroll
      for (int r = 0; r < 4; ++r) {
        if (H == 3) xp[(r0 + rl + r) * 256 + ((col & 63) << 2) + (col >> 6)] = (f16)acc[j][r];
        else        xp[(r0 + rl + r) * 64 + col] = (f16)acc[j][r];
      }
    } else if (j < JW0) {
      int cc = col - H * 64;
      if (cc >= 0 && cc < 2 * H) {
        int hh = cc >> 1;
        #pragma unroll
        for (int r = 0; r < 4; ++r) {
          if (cc & 1) ald[(r0 + rl + r) * H + hh] = acc[j][r];
          else        als[(r0 + rl + r) * H + hh] = acc[j][r];
        }
      }
    } else {
      int e = col - WL0;
      f16 o[4] = {(f16)acc[j][0], (f16)acc[j][1], (f16)acc[j][2], (f16)acc[j][3]};
      *(uint64_t*)&stage[e * 72 + rl] = *(uint64_t*)o;
    }
  }
  __syncthreads();
  {
    int e = t >> 2, seg = (t & 3) << 4;
    float4 v0 = *(const float4*)&stage[e * 72 + seg];
    float4 v1 = *(const float4*)&stage[e * 72 + seg + 8];
    f16* dst = HWlT + (((size_t)((b << 6) + e)) << 12) + n0 + seg;
    *(float4*)dst = v0;
    *(float4*)(dst + 8) = v1;
  }
}

// ---------------- layer-0 prep: h @ [Wl0|Wo] -> HWlT + orig ----------------
__global__ __launch_bounds__(256) void k_prep0(const float* __restrict__ h, const f16* __restrict__ W0h,
                                               f16* __restrict__ HWlT, f16* __restrict__ orig) {
  __shared__ f16 Ah[64 * 72];
  __shared__ f16 Bh[128 * 72];
  __shared__ f16 stage[64 * 72];
  const int t = threadIdx.x, lane = t & 63, w = t >> 6;
  const size_t r0 = (size_t)blockIdx.x * 64;
  const int b = (int)(r0 >> 12), n0 = (int)(r0 & 4095);
  #pragma unroll
  for (int i = 0; i < 4; ++i) {
    int idx = t + (i << 8);
    int row = idx >> 4, k4 = (idx & 15) << 2;
    float4 v = *(const float4*)&h[(r0 + row) * 64 + k4];
    f16 o[4] = {(f16)v.x, (f16)v.y, (f16)v.z, (f16)v.w};
    *(uint64_t*)&Ah[row * 72 + k4] = *(uint64_t*)o;
  }
  for (int i = t; i < 128 * 16; i += 256) {
    int row = i >> 4, k4 = (i & 15) << 2;
    *(uint64_t*)&Bh[row * 72 + k4] = *(const uint64_t*)&W0h[(size_t)row * 64 + k4];
  }
  __syncthreads();
  const int l15 = lane & 15, lhi = lane >> 4;
  f32x4 acc[8] = {};
  #pragma unroll
  for (int kk = 0; kk < 2; ++kk) {
    half8 af = *(const half8*)&Ah[(w * 16 + l15) * 72 + kk * 32 + lhi * 8];
    #pragma unroll
    for (int j = 0; j < 8; ++j) {
      half8 bf = *(const half8*)&Bh[(j * 16 + l15) * 72 + kk * 32 + lhi * 8];
      acc[j] = __builtin_amdgcn_mfma_f32_16x16x32_f16(af, bf, acc[j], 0, 0, 0);
    }
  }
  const int rl = w * 16 + lhi * 4;
  #pragma unroll
  for (int j = 0; j < 8; ++j) {
    int col = j * 16 + l15;
    if (j < 4) {
      f16 o[4] = {(f16)acc[j][0], (f16)acc[j][1], (f16)acc[j][2], (f16)acc[j][3]};
      *(uint64_t*)&stage[col * 72 + rl] = *(uint64_t*)o;
    } else {
      #pragma unroll
      for (int r = 0; r < 4; ++r)
        orig[(r0 + rl + r) * 64 + (col - 64)] = (f16)acc[j][r];
    }
  }
  __syncthreads();
  {
    int e = t >> 2, seg = (t & 3) << 4;
    float4 v0 = *(const float4*)&stage[e * 72 + seg];
    float4 v1 = *(const float4*)&stage[e * 72 + seg + 8];
    f16* dst = HWlT + (((size_t)((b << 6) + e)) << 12) + n0 + seg;
    *(float4*)dst = v0;
    *(float4*)(dst + 8) = v1;
  }
}

// ---------------- Mals[b][h] = max_n als ----------------
template<int H>
__global__ __launch_bounds__(256) void k_maxals(const float* __restrict__ als, float* __restrict__ Mals) {
  __shared__ float red[256];
  int b = blockIdx.x, t = threadIdx.x;
  size_t rbase = (size_t)b << 12;
  for (int h = 0; h < H; ++h) {
    float m = -1e30f;
    for (int n = t; n < NN; n += 256) m = fmaxf(m, als[(rbase + n) * H + h]);
    red[t] = m;
    __syncthreads();
    for (int d = 128; d; d >>= 1) {
      if (t < d) red[t] = fmaxf(red[t], red[t + d]);
      __syncthreads();
    }
    if (t == 0) Mals[b * H + h] = red[0];
    __syncthreads();
  }
}

// ---------------- edge weights (H==3: stride-4 padded for float4 loads) ----------------
template<int H>
__global__ __launch_bounds__(256) void k_wts(const float* __restrict__ als, const float* __restrict__ ald,
                                             const float* __restrict__ Mals, const int* __restrict__ esrc,
                                             const int* __restrict__ edst, float* __restrict__ wts) {
  const int WST = (H == 3) ? 4 : 1;
  int t = threadIdx.x, lane = t & 63, w = t >> 6;
  int gw = blockIdx.x * 4 + w;
  int b = gw & 15;
  int p = ((gw >> 4) << 6) + lane;
  size_t rbase = (size_t)b << 12;
  int s = esrc[p], n = edst[p];
  float* dst = wts + ((size_t)b * ETOT + p) * WST;
  #pragma unroll
  for (int h = 0; h < H; ++h) {
    float ad = ald[(rbase + n) * H + h];
    float B = Mals[b * H + h] + ad;
    float T = B > 0.f ? B : 0.2f * B;
    float ev = als[(rbase + s) * H + h] + ad;
    ev = ev > 0.f ? ev : 0.2f * ev;
    dst[h] = __expf(ev - T);
  }
}

// ---------------- GAT aggregation ----------------
template<int H>
__global__ __launch_bounds__(256) void k_agg(const f16* __restrict__ xp, const float* __restrict__ wts,
                                             const int* __restrict__ offs, const int* __restrict__ cnt,
                                             const int* __restrict__ esrc, const float* __restrict__ bg,
                                             float* __restrict__ hcur) {
  const int WST = (H == 3) ? 4 : 1;
  __shared__ float wbuf[4][64 * WST];
  __shared__ int   sbuf[4][64];
  int t = threadIdx.x, lane = t & 63, wv = t >> 6;
  int wid = (blockIdx.x << 2) + wv;
  int b = wid >> 12, n = wid & 4095;
  size_t rbase = (size_t)b << 12;
  int o = offs[n], c = cnt[n];
  const float* wsrc = wts + ((size_t)b * ETOT + o) * WST;
  float z[H], acc[H];
  #pragma unroll
  for (int hh = 0; hh < H; ++hh) { z[hh] = 0.f; acc[hh] = 0.f; }
  for (int e0 = 0; e0 < c; e0 += 64) {
    int ce = min(64, c - e0);
    if (lane < ce) {
      sbuf[wv][lane] = esrc[o + e0 + lane];
      if (H == 3) *(float4*)&wbuf[wv][lane * 4] = *(const float4*)&wsrc[(size_t)(e0 + lane) * 4];
      else        wbuf[wv][lane] = wsrc[e0 + lane];
    }
    #pragma unroll 4
    for (int e = 0; e < ce; ++e) {
      int s = sbuf[wv][e];
      if (H == 3) {
        float4 w4 = *(const float4*)&wbuf[wv][e * 4];       // broadcast ds_read_b128
        f16x4 q = *(const f16x4*)(xp + (((size_t)(rbase + s)) << 8) + (lane << 2));
        z[0] += w4.x; acc[0] = fmaf(w4.x, (float)q[0], acc[0]);
        z[1] += w4.y; acc[1] = fmaf(w4.y, (float)q[1], acc[1]);
        z[2] += w4.z; acc[2] = fmaf(w4.z, (float)q[2], acc[2]);
      } else {
        float wv_ = wbuf[wv][e];
        float xv = (float)xp[(((size_t)(rbase + s)) << 6) + lane];
        z[0] += wv_; acc[0] = fmaf(wv_, xv, acc[0]);
      }
    }
  }
  float r = 0.f;
  #pragma unroll
  for (int hh = 0; hh < H; ++hh) r += acc[hh] / z[hh];
  hcur[(rbase + n) * 64 + lane] = r * (1.f / H) + bg[lane];
}

// ---------------- layer-0 combine: pure elementwise ----------------
__global__ __launch_bounds__(256) void k_comb0e(const float* __restrict__ h, const f16* __restrict__ gp,
                                                const float* __restrict__ rowZ, const f16* __restrict__ orig,
                                                const float* __restrict__ bl, const float* __restrict__ bo,
                                                float* __restrict__ hout) {
  for (size_t i4 = (size_t)blockIdx.x * 256 + threadIdx.x; i4 < (size_t)ROWS * 16; i4 += (size_t)2048 * 256) {
    size_t i = i4 * 4;
    int d = (int)(i & 63), n = (int)((i >> 6) & 4095), b = (int)(i >> 18);
    size_t ga = ((size_t)n << 10) + (b << 6) + d;
    float zi = rowZ[n];
    f16x4 g0 = *(const f16x4*)&gp[ga];
    f16x4 g1 = *(const f16x4*)&gp[ga + (size_t)(4096 * 1024)];
    f16x4 og = *(const f16x4*)&orig[i];
    float4 hv = *(const float4*)&h[i];
    float4 o;
    float* op = &o.x;
    const float* hp = &hv.x;
    #pragma unroll
    for (int r = 0; r < 4; ++r) {
      float g = 1.f / (1.f + __expf(-(((float)g0[r] + (float)g1[r]) * zi + bl[d + r])));
      float orv = (float)og[r] + bo[d + r];
      op[r] = tanhf(hp[r]) * g + orv * (1.f - g);
    }
    *(float4*)&hout[i] = o;
  }
}

// ---------------- layer-1/2 combine: pure elementwise ----------------
template<int ACT>
__global__ __launch_bounds__(256) void k_comb12e(const float* __restrict__ h, const f16* __restrict__ gp,
                                                 const float* __restrict__ rowZ, const float* __restrict__ hcur,
                                                 const float* __restrict__ bl, float* __restrict__ hout) {
  for (size_t i4 = (size_t)blockIdx.x * 256 + threadIdx.x; i4 < (size_t)ROWS * 16; i4 += (size_t)2048 * 256) {
    size_t i = i4 * 4;
    int d = (int)(i & 63), n = (int)((i >> 6) & 4095), b = (int)(i >> 18);
    size_t ga = ((size_t)n << 10) + (b << 6) + d;
    float zi = rowZ[n];
    f16x4 g0 = *(const f16x4*)&gp[ga];
    f16x4 g1 = *(const f16x4*)&gp[ga + (size_t)(4096 * 1024)];
    float4 hv = *(const float4*)&h[i];
    float4 cv = *(const float4*)&hcur[i];
    float4 o;
    float* op = &o.x;
    const float* hp = &hv.x;
    const float* cp = &cv.x;
    #pragma unroll
    for (int r = 0; r < 4; ++r) {
      float g = 1.f / (1.f + __expf(-(((float)g0[r] + (float)g1[r]) * zi + bl[d + r])));
      float act = ACT ? fmaxf(cp[r], 0.f) : (cp[r] > 0.f ? cp[r] : 0.01f * cp[r]);
      op[r] = act * g + hp[r] * (1.f - g);
    }
    *(float4*)&hout[i] = o;
  }
}

// ---------------- host launch ----------------
extern "C" void kernel_launch(void* const* d_in, const int* in_sizes, int n_in,
                              void* d_out, int out_size, void* d_ws, size_t ws_size,
                              hipStream_t stream) {
  (void)in_sizes; (void)n_in; (void)out_size; (void)ws_size;
  const float* inp  = (const float*)d_in[0];
  const int*   ei   = (const int*)d_in[1];
  const float* Wseq = (const float*)d_in[2];
  const float* bseq = (const float*)d_in[3];
  const float* SE   = (const float*)d_in[4];
  const float* TE   = (const float*)d_in[5];
  const float* Wg[3]   = {(const float*)d_in[6],  (const float*)d_in[12], (const float*)d_in[18]};
  const float* asrc[3] = {(const float*)d_in[7],  (const float*)d_in[13], (const float*)d_in[19]};
  const float* adst[3] = {(const float*)d_in[8],  (const float*)d_in[14], (const float*)d_in[20]};
  const float* bgp[3]  = {(const float*)d_in[9],  (const float*)d_in[15], (const float*)d_in[21]};
  const float* Wl[3]   = {(const float*)d_in[10], (const float*)d_in[16], (const float*)d_in[22]};
  const float* bl[3]   = {(const float*)d_in[11], (const float*)d_in[17], (const float*)d_in[23]};
  const float* Wo = (const float*)d_in[24];
  const float* bo = (const float*)d_in[25];
  float* out = (float*)d_out;

  uint8_t* ws = (uint8_t*)d_ws;
  size_t o = 0;
  auto nxt = [&](size_t sz) { void* p = ws + o; o += (sz + 255) & ~(size_t)255; return p; };
  f16*   Af   = (f16*)  nxt((size_t)NN * NN * sizeof(f16));            // 32 MB
  f16*   HWlT = (f16*)  nxt((size_t)1024 * NN * sizeof(f16));          // 8 MB
  float* h    = (float*)nxt((size_t)ROWS * 64 * 4);                    // 16 MB
  f16*   gp   = (f16*)  nxt((size_t)KSPLIT * NN * 1024 * sizeof(f16)); // 16 MB
  f16*   xp   = (f16*)  nxt((size_t)ROWS * 256 * sizeof(f16));         // 32 MB (H=3 interleaved)
  f16*   orig = (f16*)  nxt((size_t)ROWS * 64 * sizeof(f16));          // 8 MB
  float* als  = (float*)nxt((size_t)ROWS * 3 * 4);
  float* ald  = (float*)nxt((size_t)ROWS * 3 * 4);
  float* hcur = (float*)nxt((size_t)ROWS * 64 * 4);                    // 16 MB
  float* rowZ = (float*)nxt((size_t)NN * 4);
  float* Zpart= (float*)nxt((size_t)64 * NN * 4);                      // 1 MB
  f16*   SEh  = (f16*)  nxt((size_t)NN * 64 * sizeof(f16));
  f16*   TEh  = (f16*)  nxt((size_t)NN * 64 * sizeof(f16));
  f16*   Wgh1 = (f16*)  nxt((size_t)288 * 64 * sizeof(f16));
  f16*   Wgh2 = (f16*)  nxt((size_t)144 * 64 * sizeof(f16));
  f16*   W0h  = (f16*)  nxt((size_t)128 * 64 * sizeof(f16));
  float* wts  = (float*)nxt((size_t)NB * ETOT * 4 * 4);                // 9.4 MB (stride-4)
  float* Mals = (float*)nxt((size_t)NB * 3 * 4);
  int*   cnt  = (int*)  nxt((size_t)NN * 4);
  int*   curp = (int*)  nxt((size_t)NN * 4);
  int*   offs = (int*)  nxt((size_t)NN * 4);
  int*   esrc = (int*)  nxt((size_t)ETOT * 4);
  int*   edst = (int*)  nxt((size_t)ETOT * 4);

  static bool attr_set = false;
  if (!attr_set) {
    hipFuncSetAttribute((const void*)k_gemm8, hipFuncAttributeMaxDynamicSharedMemorySize, 147456);
    attr_set = true;
  }

  dim3 blk(256);
  // CSR build + independent prep
  k_zero2<<<32, blk, 0, stream>>>(cnt, curp);
  k_count<<<144, blk, 0, stream>>>(ei, cnt);
  k_scan<<<1, blk, 0, stream>>>(cnt, offs);
  k_fill<<<144, blk, 0, stream>>>(ei, offs, curp, esrc, edst);
  k_allprep<<<40, blk, 0, stream>>>(Wg[1], asrc[1], adst[1], Wl[1], Wgh1,
                                    Wg[2], asrc[2], adst[2], Wl[2], Wgh2,
                                    Wl[0], Wo, W0h);
  // h0 + adjacency
  k_seq<<<1024, blk, 0, stream>>>(inp, Wseq, bseq, h);
  k_cast<<<320, blk, 0, stream>>>(SE, TE, SEh, TEh);
  k_adjmm<<<dim3(32, 32), blk, 0, stream>>>(SEh, TEh, Af, Zpart);
  k_rowz<<<16, blk, 0, stream>>>(Zpart, rowZ);
  // ---- layer 0 ----
  k_prep0<<<1024, blk, 0, stream>>>(h, W0h, HWlT, orig);
  k_gemm8<<<256, 512, 147456, stream>>>(Af, HWlT, gp);
  k_comb0e<<<2048, blk, 0, stream>>>(h, gp, rowZ, orig, bl[0], bo, h);
  // ---- layer 1 ----
  k_xpmm<3, 272><<<1024, blk, 0, stream>>>(h, Wgh1, xp, als, ald, HWlT);
  k_maxals<3><<<16, blk, 0, stream>>>(als, Mals);
  k_wts<3><<<2304, blk, 0, stream>>>(als, ald, Mals, esrc, edst, wts);
  k_gemm8<<<256, 512, 147456, stream>>>(Af, HWlT, gp);
  k_agg<3><<<16384, blk, 0, stream>>>(xp, wts, offs, cnt, esrc, bgp[1], hcur);
  k_comb12e<0><<<2048, blk, 0, stream>>>(h, gp, rowZ, hcur, bl[1], h);
  // ---- layer 2 ----
  k_xpmm<1, 144><<<1024, blk, 0, stream>>>(h, Wgh2, xp, als, ald, HWlT);
  k_maxals<1><<<16, blk, 0, stream>>>(als, Mals);
  k_wts<1><<<2304, blk, 0, stream>>>(als, ald, Mals, esrc, edst, wts);
  k_gemm8<<<256, 512, 147456, stream>>>(Af, HWlT, gp);
  k_agg<1><<<16384, blk, 0, stream>>>(xp, wts, offs, cnt, esrc, bgp[2], hcur);
  k_comb12e<1><<<2048, blk, 0, stream>>>(h, gp, rowZ, hcur, bl[2], out);
}

// Round 13
// 308.420 us; speedup vs baseline: 1.1737x; 1.0649x over previous
//
#include <hip/hip_runtime.h>
#include <stdint.h>

// ---- problem constants ----
#define NB 16        // batch
#define NN 4096      // nodes
#define DD 64        // feature dim (== S)
#define EE 32768     // edges (before self loops)
#define ETOT 36864   // edges + self loops
#define ROWS 65536   // B*N
#define KSPLIT 2

typedef _Float16 f16;
typedef f16   half8 __attribute__((ext_vector_type(8)));
typedef f16   f16x8 __attribute__((ext_vector_type(8)));
typedef f16   f16x4 __attribute__((ext_vector_type(4)));
typedef float f32x4 __attribute__((ext_vector_type(4)));

__device__ __forceinline__ void gload16(const f16* g, f16* l) {
  __builtin_amdgcn_global_load_lds((const __attribute__((address_space(1))) void*)g,
                                   (__attribute__((address_space(3))) void*)l, 16, 0, 0);
}

// ---------------- CSR build ----------------
__global__ __launch_bounds__(256) void k_zero2(int* a, int* b) {
  int i = blockIdx.x * 256 + threadIdx.x;
  if (i < NN) a[i] = 0;
  else if (i < 2 * NN) b[i - NN] = 0;
}

__global__ __launch_bounds__(256) void k_count(const int* __restrict__ ei, int* __restrict__ cnt) {
  int t = blockIdx.x * 256 + threadIdx.x;
  if (t >= ETOT) return;
  int d = (t < EE) ? ei[EE + t] : (t - EE);
  atomicAdd(&cnt[d], 1);
}

__global__ __launch_bounds__(256) void k_scan(const int* __restrict__ cnt, int* __restrict__ offs) {
  __shared__ int part[256];
  int t = threadIdx.x;
  int loc[16]; int s = 0;
  #pragma unroll
  for (int i = 0; i < 16; ++i) { int v = cnt[(t << 4) + i]; loc[i] = s; s += v; }
  part[t] = s;
  __syncthreads();
  int own = s;
  for (int d = 1; d < 256; d <<= 1) {
    int u = (t >= d) ? part[t - d] : 0;
    __syncthreads();
    part[t] += u;
    __syncthreads();
  }
  int base = part[t] - own;
  #pragma unroll
  for (int i = 0; i < 16; ++i) offs[(t << 4) + i] = base + loc[i];
}

__global__ __launch_bounds__(256) void k_fill(const int* __restrict__ ei, const int* __restrict__ offs,
                                              int* __restrict__ cur, int* __restrict__ esrc,
                                              int* __restrict__ edst) {
  int t = blockIdx.x * 256 + threadIdx.x;
  if (t >= ETOT) return;
  int s, d;
  if (t < EE) { s = ei[t]; d = ei[EE + t]; } else { s = d = t - EE; }
  int p = atomicAdd(&cur[d], 1);
  esrc[offs[d] + p] = s;
  edst[offs[d] + p] = d;
}

// ---------------- seq_linear: h = in^T @ Wseq + b + in^T ----------------
__global__ __launch_bounds__(256) void k_seq(const float* __restrict__ inp, const float* __restrict__ Wseq,
                                             const float* __restrict__ bseq, float* __restrict__ h) {
  __shared__ float X[64 * 68];
  int t = threadIdx.x;
  int b = blockIdx.x >> 6, n0 = (blockIdx.x & 63) << 6;
  #pragma unroll
  for (int i = 0; i < 16; ++i) {
    int idx = t + (i << 8);
    int s = idx >> 6, nl = idx & 63;
    X[nl * 68 + s] = inp[((size_t)((b << 6) + s) << 12) + n0 + nl];
  }
  __syncthreads();
  int c = t & 63, rg = t >> 6;
  float Wc[64];
  #pragma unroll
  for (int k = 0; k < 64; ++k) Wc[k] = Wseq[(k << 6) + c];
  float bc = bseq[c];
  for (int rr = 0; rr < 16; ++rr) {
    int r = (rg << 4) + rr;
    float a = bc + X[r * 68 + c];
    #pragma unroll
    for (int k4 = 0; k4 < 16; ++k4) {
      float4 x = *(const float4*)&X[r * 68 + (k4 << 2)];
      a = fmaf(x.x, Wc[4*k4+0], a); a = fmaf(x.y, Wc[4*k4+1], a);
      a = fmaf(x.z, Wc[4*k4+2], a); a = fmaf(x.w, Wc[4*k4+3], a);
    }
    h[((size_t)(b << 12) + n0 + r) * 64 + c] = a;
  }
}

// ---------------- adjacency MFMA GEMM: single-stage, exp(relu) epilogue ----------------
__global__ __launch_bounds__(256) void k_adjmm(const f16* __restrict__ SEh, const f16* __restrict__ TEh,
                                               f16* __restrict__ A, float* __restrict__ Zpart) {
  __shared__ f16 Al[2][128 * 32];
  __shared__ f16 Bl[2][128 * 32];
  const int t = threadIdx.x, lane = t & 63, w = t >> 6;
  const int m0 = blockIdx.y << 7, j0 = blockIdx.x << 7;
  const int l15 = lane & 15, lhi = lane >> 4;
  const int wm = (w >> 1) << 6, wj = (w & 1) << 6;
  f32x4 acc[4][4] = {};
  const int c0 = (w << 6) + lane;
  const int row0 = c0 >> 2, ko0 = (c0 & 3) << 3;
  const int c1 = c0 + 256;
  const int row1 = c1 >> 2, ko1 = (c1 & 3) << 3;
  const f16* ga0 = SEh + (size_t)(m0 + row0) * 64 + ko0;
  const f16* ga1 = SEh + (size_t)(m0 + row1) * 64 + ko1;
  const f16* gb0 = TEh + (size_t)(j0 + row0) * 64 + ko0;
  const f16* gb1 = TEh + (size_t)(j0 + row1) * 64 + ko1;
  #pragma unroll
  for (int kt = 0; kt < 2; ++kt) {
    const int kof = kt << 5;
    gload16(ga0 + kof, Al[kt] + c0 * 8);
    gload16(ga1 + kof, Al[kt] + c1 * 8);
    gload16(gb0 + kof, Bl[kt] + c0 * 8);
    gload16(gb1 + kof, Bl[kt] + c1 * 8);
  }
  __syncthreads();
  #pragma unroll
  for (int kt = 0; kt < 2; ++kt) {
    half8 af[4], bf[4];
    #pragma unroll
    for (int i = 0; i < 4; ++i) {
      af[i] = *(const half8*)(Al[kt] + (wm + i * 16 + l15) * 32 + lhi * 8);
      bf[i] = *(const half8*)(Bl[kt] + (wj + i * 16 + l15) * 32 + lhi * 8);
    }
    #pragma unroll
    for (int mi = 0; mi < 4; ++mi)
      #pragma unroll
      for (int nj = 0; nj < 4; ++nj)
        acc[mi][nj] = __builtin_amdgcn_mfma_f32_16x16x32_f16(af[mi], bf[nj], acc[mi][nj], 0, 0, 0);
  }
  float rs[4][4];
  #pragma unroll
  for (int mi = 0; mi < 4; ++mi)
    #pragma unroll
    for (int r = 0; r < 4; ++r) rs[mi][r] = 0.f;
  #pragma unroll
  for (int mi = 0; mi < 4; ++mi)
    #pragma unroll
    for (int nj = 0; nj < 4; ++nj)
      #pragma unroll
      for (int r = 0; r < 4; ++r) {
        int row = m0 + wm + mi * 16 + lhi * 4 + r;
        int col = j0 + wj + nj * 16 + l15;
        float e = __expf(fmaxf(acc[mi][nj][r], 0.f));
        f16 eh = (f16)e;
        A[((size_t)row << 12) + col] = eh;
        rs[mi][r] += (float)eh;
      }
  #pragma unroll
  for (int mi = 0; mi < 4; ++mi)
    #pragma unroll
    for (int r = 0; r < 4; ++r) {
      float s = rs[mi][r];
      s += __shfl_xor(s, 1); s += __shfl_xor(s, 2);
      s += __shfl_xor(s, 4); s += __shfl_xor(s, 8);
      rs[mi][r] = s;
    }
  if (l15 == 0) {
    int p = (blockIdx.x << 1) + (w & 1);
    #pragma unroll
    for (int mi = 0; mi < 4; ++mi)
      #pragma unroll
      for (int r = 0; r < 4; ++r)
        Zpart[((size_t)p << 12) + m0 + wm + mi * 16 + lhi * 4 + r] = rs[mi][r];
  }
}

__global__ __launch_bounds__(256) void k_rowz(const float* __restrict__ Zpart, float* __restrict__ rowZ) {
  int row = blockIdx.x * 256 + threadIdx.x;
  float s = 0.f;
  #pragma unroll 8
  for (int p = 0; p < 64; ++p) s += Zpart[((size_t)p << 12) + row];
  rowZ[row] = 1.f / s;
}

// ---------------- big GEMM, 8-phase-style schedule; 4x2 wave decomposition ----------------
#define NKT 32
__global__ __launch_bounds__(512) void k_gemm8(const f16* __restrict__ A, const f16* __restrict__ BT,
                                               f16* __restrict__ Cout) {
  extern __shared__ f16 smem[];
  const int t = threadIdx.x, lane = t & 63, wid = t >> 6;
  const int wr = wid >> 1, wc = wid & 1;          // 4 m-groups x 2 j-groups, 64x64 per wave
  const int l15 = lane & 15, lhi = lane >> 4;
  const int h7 = l15 & 7;
  const int wgid = blockIdx.x;
  const int nid = (wgid & 7) * 32 + (wgid >> 3);
  const int z = nid >> 7, rem = nid & 127;
  const int m0 = (rem >> 3) << 8;
  const int j0 = (rem & 7) << 7;
  const size_t kbase = (size_t)z << 11;
  f16* __restrict__ Cz = Cout + ((size_t)z << 22);

  const f16* gA[4]; int lA[4];
  #pragma unroll
  for (int i = 0; i < 4; ++i) {
    int s = t + (i << 9), row = s >> 3, sl = (s & 7) ^ (row & 7);
    gA[i] = A + (size_t)(m0 + row) * 4096 + kbase + sl * 8;
    lA[i] = s * 8;
  }
  const f16* gB[2]; int lB[2];
  #pragma unroll
  for (int i = 0; i < 2; ++i) {
    int s = t + (i << 9), row = s >> 3, sl = (s & 7) ^ (row & 7);
    gB[i] = BT + (size_t)(j0 + row) * 4096 + kbase + sl * 8;
    lB[i] = 16384 + s * 8;
  }
  #define SA(buf, kt, i) gload16(gA[i] + (kt) * 64, smem + (buf) * 24576 + lA[i])
  #define SB(buf, kt, i) gload16(gB[i] + (kt) * 64, smem + (buf) * 24576 + lB[i])

  const int rbase = wr << 6;
  const int cbase = wc << 6;
  f32x4 acc[4][4] = {};

  #pragma unroll
  for (int i = 0; i < 4; ++i) SA(0, 0, i);
  #pragma unroll
  for (int i = 0; i < 2; ++i) SB(0, 0, i);
  #pragma unroll
  for (int i = 0; i < 4; ++i) SA(1, 1, i);
  #pragma unroll
  for (int i = 0; i < 2; ++i) SB(1, 1, i);
  asm volatile("s_waitcnt vmcnt(6)" ::: "memory");
  __builtin_amdgcn_sched_barrier(0);
  __builtin_amdgcn_s_barrier();
  __builtin_amdgcn_sched_barrier(0);

  int b0 = 0, b1 = 1, b2 = 2;
  for (int kt = 0; kt < NKT; ++kt) {
    const f16* Ab = smem + b0 * 24576;
    const f16* Bb = Ab + 16384;
    const bool pf = (kt + 2 < NKT);
    {
      half8 af[4], bf[4];
      #pragma unroll
      for (int mi = 0; mi < 4; ++mi) {
        int row = rbase + mi * 16 + l15;
        af[mi] = *(const half8*)(Ab + row * 64 + (lhi ^ h7) * 8);
      }
      #pragma unroll
      for (int nj = 0; nj < 4; ++nj) {
        int row = cbase + nj * 16 + l15;
        bf[nj] = *(const half8*)(Bb + row * 64 + (lhi ^ h7) * 8);
      }
      if (pf) { SA(b2, kt + 2, 0); SA(b2, kt + 2, 1); SA(b2, kt + 2, 2); }
      __builtin_amdgcn_s_setprio(1);
      #pragma unroll
      for (int mi = 0; mi < 4; ++mi)
        #pragma unroll
        for (int nj = 0; nj < 4; ++nj)
          acc[mi][nj] = __builtin_amdgcn_mfma_f32_16x16x32_f16(af[mi], bf[nj], acc[mi][nj], 0, 0, 0);
      __builtin_amdgcn_s_setprio(0);
    }
    __builtin_amdgcn_s_barrier();
    __builtin_amdgcn_sched_barrier(0);
    {
      half8 af[4], bf[4];
      #pragma unroll
      for (int mi = 0; mi < 4; ++mi) {
        int row = rbase + mi * 16 + l15;
        af[mi] = *(const half8*)(Ab + row * 64 + ((4 + lhi) ^ h7) * 8);
      }
      #pragma unroll
      for (int nj = 0; nj < 4; ++nj) {
        int row = cbase + nj * 16 + l15;
        bf[nj] = *(const half8*)(Bb + row * 64 + ((4 + lhi) ^ h7) * 8);
      }
      if (pf) { SA(b2, kt + 2, 3); SB(b2, kt + 2, 0); SB(b2, kt + 2, 1); }
      __builtin_amdgcn_s_setprio(1);
      #pragma unroll
      for (int mi = 0; mi < 4; ++mi)
        #pragma unroll
        for (int nj = 0; nj < 4; ++nj)
          acc[mi][nj] = __builtin_amdgcn_mfma_f32_16x16x32_f16(af[mi], bf[nj], acc[mi][nj], 0, 0, 0);
      __builtin_amdgcn_s_setprio(0);
    }
    if (kt < NKT - 2)       asm volatile("s_waitcnt vmcnt(6)" ::: "memory");
    else if (kt == NKT - 2) asm volatile("s_waitcnt vmcnt(0)" ::: "memory");
    __builtin_amdgcn_sched_barrier(0);
    __builtin_amdgcn_s_barrier();
    __builtin_amdgcn_sched_barrier(0);
    int tb = b0; b0 = b1; b1 = b2; b2 = tb;
  }
  #undef SA
  #undef SB
  #pragma unroll
  for (int mi = 0; mi < 4; ++mi)
    #pragma unroll
    for (int nj = 0; nj < 4; ++nj)
      #pragma unroll
      for (int r = 0; r < 4; ++r) {
        int row = m0 + rbase + mi * 16 + (lhi << 2) + r;
        int col = j0 + cbase + nj * 16 + l15;
        Cz[(size_t)row * 1024 + col] = (f16)acc[mi][nj][r];
      }
}

// ---------------- fused prep: Wgh1, Wgh2, W0h, SE cast, TE cast ----------------
template<int H, int NP>
__device__ __forceinline__ void wprep_body(const float* __restrict__ Wg, const float* __restrict__ asrc,
                                           const float* __restrict__ adst, const float* __restrict__ Wl,
                                           f16* __restrict__ Wgh, int bid, int t) {
  const int WL0 = H * 64 + 16;
  for (int i = bid * 256 + t; i < NP * 64; i += 16 * 256) {
    int j = i >> 6, k = i & 63;
    float v;
    if (j < H * 64) {
      v = Wg[(size_t)k * (H * 64) + j];
    } else if (j < H * 64 + 2 * H) {
      int cc = j - H * 64, hh = cc >> 1;
      const float* a = ((cc & 1) ? adst : asrc) + (hh << 6);
      const float* wrow = Wg + (size_t)k * (H * 64) + (hh << 6);
      float s = 0.f;
      #pragma unroll 16
      for (int c = 0; c < 64; ++c) s = fmaf(wrow[c], a[c], s);
      v = s;
    } else if (j >= WL0 && j < WL0 + 64) {
      v = Wl[(k << 6) + (j - WL0)];
    } else v = 0.f;
    Wgh[(size_t)j * 64 + k] = (f16)v;
  }
}

__global__ __launch_bounds__(256) void k_allprep(
    const float* __restrict__ Wg1, const float* __restrict__ as1, const float* __restrict__ ad1,
    const float* __restrict__ Wl1, f16* __restrict__ Wgh1,
    const float* __restrict__ Wg2, const float* __restrict__ as2, const float* __restrict__ ad2,
    const float* __restrict__ Wl2, f16* __restrict__ Wgh2,
    const float* __restrict__ Wl0, const float* __restrict__ Wo, f16* __restrict__ W0h,
    const float* __restrict__ SE, const float* __restrict__ TE,
    f16* __restrict__ SEh, f16* __restrict__ TEh) {
  __shared__ float X[64 * 65];
  int bid = blockIdx.x, t = threadIdx.x;
  if (bid < 16) { wprep_body<3, 272>(Wg1, as1, ad1, Wl1, Wgh1, bid, t); return; }
  if (bid < 32) { wprep_body<1, 144>(Wg2, as2, ad2, Wl2, Wgh2, bid - 16, t); return; }
  if (bid < 40) {
    for (int i = (bid - 32) * 256 + t; i < 128 * 64; i += 8 * 256) {
      int j = i >> 6, k = i & 63;
      float v = (j < 64) ? Wl0[(k << 6) + j] : Wo[(k << 6) + (j - 64)];
      W0h[(size_t)j * 64 + k] = (f16)v;
    }
    return;
  }
  if (bid < 296) {                     // SE cast
    int i = ((bid - 40) * 256 + t) * 4;
    float4 v = *(const float4*)(SE + i);
    f16 o[4] = {(f16)v.x, (f16)v.y, (f16)v.z, (f16)v.w};
    *(uint64_t*)(SEh + i) = *(uint64_t*)o;
    return;
  }
  // TE transpose-cast
  int j0 = (bid - 296) << 6;
  #pragma unroll
  for (int i = 0; i < 16; ++i) {
    int idx = t + (i << 8);
    int k = idx >> 6, jl = idx & 63;
    X[jl * 65 + k] = TE[((size_t)k << 12) + j0 + jl];
  }
  __syncthreads();
  int jl = t >> 2, kg = t & 3;
  f16 o[16];
  #pragma unroll
  for (int i = 0; i < 16; ++i) o[i] = (f16)X[jl * 65 + (kg << 4) + i];
  f16* dst = TEh + ((size_t)(j0 + jl) << 6) + (kg << 4);
  *(uint64_t*)(dst + 0) = *(uint64_t*)(o + 0);
  *(uint64_t*)(dst + 4) = *(uint64_t*)(o + 4);
  *(uint64_t*)(dst + 8) = *(uint64_t*)(o + 8);
  *(uint64_t*)(dst + 12) = *(uint64_t*)(o + 12);
}

// ---------------- xp = h @ Wg via MFMA + als/ald + HWlT ----------------
template<int H, int NP>
__global__ __launch_bounds__(256) void k_xpmm(const float* __restrict__ h, const f16* __restrict__ Wgh,
                                              f16* __restrict__ xp, float* __restrict__ als,
                                              float* __restrict__ ald, f16* __restrict__ HWlT) {
  const int WL0 = H * 64 + 16, JW0 = WL0 / 16, NT = NP / 16;
  __shared__ f16 Ah[64 * 72];
  __shared__ f16 Bh[NP * 72];
  __shared__ f16 stage[64 * 72];
  const int t = threadIdx.x, lane = t & 63, w = t >> 6;
  const size_t r0 = (size_t)blockIdx.x * 64;
  const int b = (int)(r0 >> 12), n0 = (int)(r0 & 4095);
  #pragma unroll
  for (int i = 0; i < 4; ++i) {
    int idx = t + (i << 8);
    int row = idx >> 4, k4 = (idx & 15) << 2;
    float4 v = *(const float4*)&h[(r0 + row) * 64 + k4];
    f16 o[4] = {(f16)v.x, (f16)v.y, (f16)v.z, (f16)v.w};
    *(uint64_t*)&Ah[row * 72 + k4] = *(uint64_t*)o;
  }
  for (int i = t; i < NP * 16; i += 256) {
    int row = i >> 4, k4 = (i & 15) << 2;
    *(uint64_t*)&Bh[row * 72 + k4] = *(const uint64_t*)&Wgh[(size_t)row * 64 + k4];
  }
  __syncthreads();
  const int l15 = lane & 15, lhi = lane >> 4;
  f32x4 acc[NT] = {};
  #pragma unroll
  for (int kk = 0; kk < 2; ++kk) {
    half8 af = *(const half8*)&Ah[(w * 16 + l15) * 72 + kk * 32 + lhi * 8];
    #pragma unroll
    for (int j = 0; j < NT; ++j) {
      half8 bf = *(const half8*)&Bh[(j * 16 + l15) * 72 + kk * 32 + lhi * 8];
      acc[j] = __builtin_amdgcn_mfma_f32_16x16x32_f16(af, bf, acc[j], 0, 0, 0);
    }
  }
  const int rl = w * 16 + lhi * 4;
  #pragma unroll
  for (int j = 0; j < NT; ++j) {
    int col = j * 16 + l15;
    if (j * 16 + 15 < H * 64) {
      #pragma unroll
      for (int r = 0; r < 4; ++r) {
        if (H == 3) xp[(r0 + rl + r) * 256 + ((col & 63) << 2) + (col >> 6)] = (f16)acc[j][r];
        else        xp[(r0 + rl + r) * 64 + col] = (f16)acc[j][r];
      }
    } else if (j < JW0) {
      int cc = col - H * 64;
      if (cc >= 0 && cc < 2 * H) {
        int hh = cc >> 1;
        #pragma unroll
        for (int r = 0; r < 4; ++r) {
          if (cc & 1) ald[(r0 + rl + r) * H + hh] = acc[j][r];
          else        als[(r0 + rl + r) * H + hh] = acc[j][r];
        }
      }
    } else {
      int e = col - WL0;
      f16 o[4] = {(f16)acc[j][0], (f16)acc[j][1], (f16)acc[j][2], (f16)acc[j][3]};
      *(uint64_t*)&stage[e * 72 + rl] = *(uint64_t*)o;
    }
  }
  __syncthreads();
  {
    int e = t >> 2, seg = (t & 3) << 4;
    float4 v0 = *(const float4*)&stage[e * 72 + seg];
    float4 v1 = *(const float4*)&stage[e * 72 + seg + 8];
    f16* dst = HWlT + (((size_t)((b << 6) + e)) << 12) + n0 + seg;
    *(float4*)dst = v0;
    *(float4*)(dst + 8) = v1;
  }
}

// ---------------- layer-0 prep: h @ [Wl0|Wo] -> HWlT + orig ----------------
__global__ __launch_bounds__(256) void k_prep0(const float* __restrict__ h, const f16* __restrict__ W0h,
                                               f16* __restrict__ HWlT, f16* __restrict__ orig) {
  __shared__ f16 Ah[64 * 72];
  __shared__ f16 Bh[128 * 72];
  __shared__ f16 stage[64 * 72];
  const int t = threadIdx.x, lane = t & 63, w = t >> 6;
  const size_t r0 = (size_t)blockIdx.x * 64;
  const int b = (int)(r0 >> 12), n0 = (int)(r0 & 4095);
  #pragma unroll
  for (int i = 0; i < 4; ++i) {
    int idx = t + (i << 8);
    int row = idx >> 4, k4 = (idx & 15) << 2;
    float4 v = *(const float4*)&h[(r0 + row) * 64 + k4];
    f16 o[4] = {(f16)v.x, (f16)v.y, (f16)v.z, (f16)v.w};
    *(uint64_t*)&Ah[row * 72 + k4] = *(uint64_t*)o;
  }
  for (int i = t; i < 128 * 16; i += 256) {
    int row = i >> 4, k4 = (i & 15) << 2;
    *(uint64_t*)&Bh[row * 72 + k4] = *(const uint64_t*)&W0h[(size_t)row * 64 + k4];
  }
  __syncthreads();
  const int l15 = lane & 15, lhi = lane >> 4;
  f32x4 acc[8] = {};
  #pragma unroll
  for (int kk = 0; kk < 2; ++kk) {
    half8 af = *(const half8*)&Ah[(w * 16 + l15) * 72 + kk * 32 + lhi * 8];
    #pragma unroll
    for (int j = 0; j < 8; ++j) {
      half8 bf = *(const half8*)&Bh[(j * 16 + l15) * 72 + kk * 32 + lhi * 8];
      acc[j] = __builtin_amdgcn_mfma_f32_16x16x32_f16(af, bf, acc[j], 0, 0, 0);
    }
  }
  const int rl = w * 16 + lhi * 4;
  #pragma unroll
  for (int j = 0; j < 8; ++j) {
    int col = j * 16 + l15;
    if (j < 4) {
      f16 o[4] = {(f16)acc[j][0], (f16)acc[j][1], (f16)acc[j][2], (f16)acc[j][3]};
      *(uint64_t*)&stage[col * 72 + rl] = *(uint64_t*)o;
    } else {
      #pragma unroll
      for (int r = 0; r < 4; ++r)
        orig[(r0 + rl + r) * 64 + (col - 64)] = (f16)acc[j][r];
    }
  }
  __syncthreads();
  {
    int e = t >> 2, seg = (t & 3) << 4;
    float4 v0 = *(const float4*)&stage[e * 72 + seg];
    float4 v1 = *(const float4*)&stage[e * 72 + seg + 8];
    f16* dst = HWlT + (((size_t)((b << 6) + e)) << 12) + n0 + seg;
    *(float4*)dst = v0;
    *(float4*)(dst + 8) = v1;
  }
}

// ---------------- Mals[b][h] = max_n als ----------------
template<int H>
__global__ __launch_bounds__(256) void k_maxals(const float* __restrict__ als, float* __restrict__ Mals) {
  __shared__ float red[256];
  int b = blockIdx.x, t = threadIdx.x;
  size_t rbase = (size_t)b << 12;
  for (int h = 0; h < H; ++h) {
    float m = -1e30f;
    for (int n = t; n < NN; n += 256) m = fmaxf(m, als[(rbase + n) * H + h]);
    red[t] = m;
    __syncthreads();
    for (int d = 128; d; d >>= 1) {
      if (t < d) red[t] = fmaxf(red[t], red[t + d]);
      __syncthreads();
    }
    if (t == 0) Mals[b * H + h] = red[0];
    __syncthreads();
  }
}

// ---------------- edge weights (H==3: stride-4 padded) ----------------
template<int H>
__global__ __launch_bounds__(256) void k_wts(const float* __restrict__ als, const float* __restrict__ ald,
                                             const float* __restrict__ Mals, const int* __restrict__ esrc,
                                             const int* __restrict__ edst, float* __restrict__ wts) {
  const int WST = (H == 3) ? 4 : 1;
  int t = threadIdx.x, lane = t & 63, w = t >> 6;
  int gw = blockIdx.x * 4 + w;
  int b = gw & 15;
  int p = ((gw >> 4) << 6) + lane;
  size_t rbase = (size_t)b << 12;
  int s = esrc[p], n = edst[p];
  float* dst = wts + ((size_t)b * ETOT + p) * WST;
  #pragma unroll
  for (int h = 0; h < H; ++h) {
    float ad = ald[(rbase + n) * H + h];
    float B = Mals[b * H + h] + ad;
    float T = B > 0.f ? B : 0.2f * B;
    float ev = als[(rbase + s) * H + h] + ad;
    ev = ev > 0.f ? ev : 0.2f * ev;
    dst[h] = __expf(ev - T);
  }
}

// ---------------- GAT aggregation + fused gate combine ----------------
template<int H, int ACT>   // ACT 0: leaky 0.01, 1: relu
__global__ __launch_bounds__(256) void k_aggc(const f16* __restrict__ xp, const float* __restrict__ wts,
                                              const int* __restrict__ offs, const int* __restrict__ cnt,
                                              const int* __restrict__ esrc, const float* __restrict__ bg,
                                              const float* __restrict__ h, const f16* __restrict__ gp,
                                              const float* __restrict__ rowZ, const float* __restrict__ bl,
                                              float* __restrict__ hout) {
  const int WST = (H == 3) ? 4 : 1;
  __shared__ float wbuf[4][64 * WST];
  __shared__ int   sbuf[4][64];
  int t = threadIdx.x, lane = t & 63, wv = t >> 6;
  int wid = (blockIdx.x << 2) + wv;
  int b = wid >> 12, n = wid & 4095;
  size_t rbase = (size_t)b << 12;
  int o = offs[n], c = cnt[n];
  const float* wsrc = wts + ((size_t)b * ETOT + o) * WST;
  float z[H], acc[H];
  #pragma unroll
  for (int hh = 0; hh < H; ++hh) { z[hh] = 0.f; acc[hh] = 0.f; }
  for (int e0 = 0; e0 < c; e0 += 64) {
    int ce = min(64, c - e0);
    if (lane < ce) {
      sbuf[wv][lane] = esrc[o + e0 + lane];
      if (H == 3) *(float4*)&wbuf[wv][lane * 4] = *(const float4*)&wsrc[(size_t)(e0 + lane) * 4];
      else        wbuf[wv][lane] = wsrc[e0 + lane];
    }
    #pragma unroll 4
    for (int e = 0; e < ce; ++e) {
      int s = sbuf[wv][e];
      if (H == 3) {
        float4 w4 = *(const float4*)&wbuf[wv][e * 4];
        f16x4 q = *(const f16x4*)(xp + (((size_t)(rbase + s)) << 8) + (lane << 2));
        z[0] += w4.x; acc[0] = fmaf(w4.x, (float)q[0], acc[0]);
        z[1] += w4.y; acc[1] = fmaf(w4.y, (float)q[1], acc[1]);
        z[2] += w4.z; acc[2] = fmaf(w4.z, (float)q[2], acc[2]);
      } else {
        float wv_ = wbuf[wv][e];
        float xv = (float)xp[(((size_t)(rbase + s)) << 6) + lane];
        z[0] += wv_; acc[0] = fmaf(wv_, xv, acc[0]);
      }
    }
  }
  float r = 0.f;
  #pragma unroll
  for (int hh = 0; hh < H; ++hh) r += acc[hh] / z[hh];
  float cv = r * (1.f / H) + bg[lane];
  // fused combine: g = sigmoid((gp0+gp1)*zi + bl); out = act(cv)*g + h*(1-g)
  size_t ga = ((size_t)n << 10) + (b << 6) + lane;
  float zi = rowZ[n];
  float g0 = (float)gp[ga], g1 = (float)gp[ga + (size_t)(4096 * 1024)];
  float g = 1.f / (1.f + __expf(-((g0 + g1) * zi + bl[lane])));
  size_t ridx = ((rbase + n) << 6) + lane;
  float hv = h[ridx];
  float act = ACT ? fmaxf(cv, 0.f) : (cv > 0.f ? cv : 0.01f * cv);
  hout[ridx] = act * g + hv * (1.f - g);
}

// ---------------- layer-0 combine: pure elementwise ----------------
__global__ __launch_bounds__(256) void k_comb0e(const float* __restrict__ h, const f16* __restrict__ gp,
                                                const float* __restrict__ rowZ, const f16* __restrict__ orig,
                                                const float* __restrict__ bl, const float* __restrict__ bo,
                                                float* __restrict__ hout) {
  for (size_t i4 = (size_t)blockIdx.x * 256 + threadIdx.x; i4 < (size_t)ROWS * 16; i4 += (size_t)2048 * 256) {
    size_t i = i4 * 4;
    int d = (int)(i & 63), n = (int)((i >> 6) & 4095), b = (int)(i >> 18);
    size_t ga = ((size_t)n << 10) + (b << 6) + d;
    float zi = rowZ[n];
    f16x4 g0 = *(const f16x4*)&gp[ga];
    f16x4 g1 = *(const f16x4*)&gp[ga + (size_t)(4096 * 1024)];
    f16x4 og = *(const f16x4*)&orig[i];
    float4 hv = *(const float4*)&h[i];
    float4 o;
    float* op = &o.x;
    const float* hp = &hv.x;
    #pragma unroll
    for (int r = 0; r < 4; ++r) {
      float g = 1.f / (1.f + __expf(-(((float)g0[r] + (float)g1[r]) * zi + bl[d + r])));
      float orv = (float)og[r] + bo[d + r];
      op[r] = tanhf(hp[r]) * g + orv * (1.f - g);
    }
    *(float4*)&hout[i] = o;
  }
}

// ---------------- host launch ----------------
extern "C" void kernel_launch(void* const* d_in, const int* in_sizes, int n_in,
                              void* d_out, int out_size, void* d_ws, size_t ws_size,
                              hipStream_t stream) {
  (void)in_sizes; (void)n_in; (void)out_size; (void)ws_size;
  const float* inp  = (const float*)d_in[0];
  const int*   ei   = (const int*)d_in[1];
  const float* Wseq = (const float*)d_in[2];
  const float* bseq = (const float*)d_in[3];
  const float* SE   = (const float*)d_in[4];
  const float* TE   = (const float*)d_in[5];
  const float* Wg[3]   = {(const float*)d_in[6],  (const float*)d_in[12], (const float*)d_in[18]};
  const float* asrc[3] = {(const float*)d_in[7],  (const float*)d_in[13], (const float*)d_in[19]};
  const float* adst[3] = {(const float*)d_in[8],  (const float*)d_in[14], (const float*)d_in[20]};
  const float* bgp[3]  = {(const float*)d_in[9],  (const float*)d_in[15], (const float*)d_in[21]};
  const float* Wl[3]   = {(const float*)d_in[10], (const float*)d_in[16], (const float*)d_in[22]};
  const float* bl[3]   = {(const float*)d_in[11], (const float*)d_in[17], (const float*)d_in[23]};
  const float* Wo = (const float*)d_in[24];
  const float* bo = (const float*)d_in[25];
  float* out = (float*)d_out;

  uint8_t* ws = (uint8_t*)d_ws;
  size_t o = 0;
  auto nxt = [&](size_t sz) { void* p = ws + o; o += (sz + 255) & ~(size_t)255; return p; };
  f16*   Af   = (f16*)  nxt((size_t)NN * NN * sizeof(f16));            // 32 MB
  f16*   HWlT = (f16*)  nxt((size_t)1024 * NN * sizeof(f16));          // 8 MB
  float* h    = (float*)nxt((size_t)ROWS * 64 * 4);                    // 16 MB
  f16*   gp   = (f16*)  nxt((size_t)KSPLIT * NN * 1024 * sizeof(f16)); // 16 MB
  f16*   xp   = (f16*)  nxt((size_t)ROWS * 256 * sizeof(f16));         // 32 MB (H=3 interleaved)
  f16*   orig = (f16*)  nxt((size_t)ROWS * 64 * sizeof(f16));          // 8 MB
  float* als  = (float*)nxt((size_t)ROWS * 3 * 4);
  float* ald  = (float*)nxt((size_t)ROWS * 3 * 4);
  float* rowZ = (float*)nxt((size_t)NN * 4);
  float* Zpart= (float*)nxt((size_t)64 * NN * 4);                      // 1 MB
  f16*   SEh  = (f16*)  nxt((size_t)NN * 64 * sizeof(f16));
  f16*   TEh  = (f16*)  nxt((size_t)NN * 64 * sizeof(f16));
  f16*   Wgh1 = (f16*)  nxt((size_t)288 * 64 * sizeof(f16));
  f16*   Wgh2 = (f16*)  nxt((size_t)144 * 64 * sizeof(f16));
  f16*   W0h  = (f16*)  nxt((size_t)128 * 64 * sizeof(f16));
  float* wts  = (float*)nxt((size_t)NB * ETOT * 4 * 4);                // 9.4 MB (stride-4)
  float* Mals = (float*)nxt((size_t)NB * 3 * 4);
  int*   cnt  = (int*)  nxt((size_t)NN * 4);
  int*   curp = (int*)  nxt((size_t)NN * 4);
  int*   offs = (int*)  nxt((size_t)NN * 4);
  int*   esrc = (int*)  nxt((size_t)ETOT * 4);
  int*   edst = (int*)  nxt((size_t)ETOT * 4);

  static bool attr_set = false;
  if (!attr_set) {
    hipFuncSetAttribute((const void*)k_gemm8, hipFuncAttributeMaxDynamicSharedMemorySize, 147456);
    attr_set = true;
  }

  dim3 blk(256);
  // CSR build + independent prep (incl. SE/TE casts)
  k_zero2<<<32, blk, 0, stream>>>(cnt, curp);
  k_count<<<144, blk, 0, stream>>>(ei, cnt);
  k_scan<<<1, blk, 0, stream>>>(cnt, offs);
  k_fill<<<144, blk, 0, stream>>>(ei, offs, curp, esrc, edst);
  k_allprep<<<360, blk, 0, stream>>>(Wg[1], asrc[1], adst[1], Wl[1], Wgh1,
                                     Wg[2], asrc[2], adst[2], Wl[2], Wgh2,
                                     Wl[0], Wo, W0h, SE, TE, SEh, TEh);
  // h0 + adjacency
  k_seq<<<1024, blk, 0, stream>>>(inp, Wseq, bseq, h);
  k_adjmm<<<dim3(32, 32), blk, 0, stream>>>(SEh, TEh, Af, Zpart);
  k_rowz<<<16, blk, 0, stream>>>(Zpart, rowZ);
  // ---- layer 0 ----
  k_prep0<<<1024, blk, 0, stream>>>(h, W0h, HWlT, orig);
  k_gemm8<<<256, 512, 147456, stream>>>(Af, HWlT, gp);
  k_comb0e<<<2048, blk, 0, stream>>>(h, gp, rowZ, orig, bl[0], bo, h);
  // ---- layer 1 ----
  k_xpmm<3, 272><<<1024, blk, 0, stream>>>(h, Wgh1, xp, als, ald, HWlT);
  k_maxals<3><<<16, blk, 0, stream>>>(als, Mals);
  k_wts<3><<<2304, blk, 0, stream>>>(als, ald, Mals, esrc, edst, wts);
  k_gemm8<<<256, 512, 147456, stream>>>(Af, HWlT, gp);
  k_aggc<3, 0><<<16384, blk, 0, stream>>>(xp, wts, offs, cnt, esrc, bgp[1], h, gp, rowZ, bl[1], h);
  // ---- layer 2 ----
  k_xpmm<1, 144><<<1024, blk, 0, stream>>>(h, Wgh2, xp, als, ald, HWlT);
  k_maxals<1><<<16, blk, 0, stream>>>(als, Mals);
  k_wts<1><<<2304, blk, 0, stream>>>(als, ald, Mals, esrc, edst, wts);
  k_gemm8<<<256, 512, 147456, stream>>>(Af, HWlT, gp);
  k_aggc<1, 1><<<16384, blk, 0, stream>>>(xp, wts, offs, cnt, esrc, bgp[2], h, gp, rowZ, bl[2], out);
}

// Round 14
// 301.862 us; speedup vs baseline: 1.1992x; 1.0217x over previous
//
#include <hip/hip_runtime.h>
#include <stdint.h>

// ---- problem constants ----
#define NB 16        // batch
#define NN 4096      // nodes
#define DD 64        // feature dim (== S)
#define EE 32768     // edges (before self loops)
#define ETOT 36864   // edges + self loops
#define ROWS 65536   // B*N
#define KSPLIT 2

typedef _Float16 f16;
typedef f16   half8 __attribute__((ext_vector_type(8)));
typedef f16   f16x8 __attribute__((ext_vector_type(8)));
typedef f16   f16x4 __attribute__((ext_vector_type(4)));
typedef float f32x4 __attribute__((ext_vector_type(4)));

__device__ __forceinline__ void gload16(const f16* g, f16* l) {
  __builtin_amdgcn_global_load_lds((const __attribute__((address_space(1))) void*)g,
                                   (__attribute__((address_space(3))) void*)l, 16, 0, 0);
}

// ---------------- CSR build ----------------
__global__ __launch_bounds__(256) void k_zero2(int* a, int* b) {
  int i = blockIdx.x * 256 + threadIdx.x;
  if (i < NN) a[i] = 0;
  else if (i < 2 * NN) b[i - NN] = 0;
}

__global__ __launch_bounds__(256) void k_count(const int* __restrict__ ei, int* __restrict__ cnt) {
  int t = blockIdx.x * 256 + threadIdx.x;
  if (t >= ETOT) return;
  int d = (t < EE) ? ei[EE + t] : (t - EE);
  atomicAdd(&cnt[d], 1);
}

__global__ __launch_bounds__(256) void k_scan(const int* __restrict__ cnt, int* __restrict__ offs) {
  __shared__ int part[256];
  int t = threadIdx.x;
  int loc[16]; int s = 0;
  #pragma unroll
  for (int i = 0; i < 16; ++i) { int v = cnt[(t << 4) + i]; loc[i] = s; s += v; }
  part[t] = s;
  __syncthreads();
  int own = s;
  for (int d = 1; d < 256; d <<= 1) {
    int u = (t >= d) ? part[t - d] : 0;
    __syncthreads();
    part[t] += u;
    __syncthreads();
  }
  int base = part[t] - own;
  #pragma unroll
  for (int i = 0; i < 16; ++i) offs[(t << 4) + i] = base + loc[i];
}

__global__ __launch_bounds__(256) void k_fill(const int* __restrict__ ei, const int* __restrict__ offs,
                                              int* __restrict__ cur, int* __restrict__ esrc,
                                              int* __restrict__ edst) {
  int t = blockIdx.x * 256 + threadIdx.x;
  if (t >= ETOT) return;
  int s, d;
  if (t < EE) { s = ei[t]; d = ei[EE + t]; } else { s = d = t - EE; }
  int p = atomicAdd(&cur[d], 1);
  esrc[offs[d] + p] = s;
  edst[offs[d] + p] = d;
}

// ---------------- seq_linear: h = in^T @ Wseq + b + in^T ----------------
__global__ __launch_bounds__(256) void k_seq(const float* __restrict__ inp, const float* __restrict__ Wseq,
                                             const float* __restrict__ bseq, float* __restrict__ h) {
  __shared__ float X[64 * 68];
  int t = threadIdx.x;
  int b = blockIdx.x >> 6, n0 = (blockIdx.x & 63) << 6;
  #pragma unroll
  for (int i = 0; i < 16; ++i) {
    int idx = t + (i << 8);
    int s = idx >> 6, nl = idx & 63;
    X[nl * 68 + s] = inp[((size_t)((b << 6) + s) << 12) + n0 + nl];
  }
  __syncthreads();
  int c = t & 63, rg = t >> 6;
  float Wc[64];
  #pragma unroll
  for (int k = 0; k < 64; ++k) Wc[k] = Wseq[(k << 6) + c];
  float bc = bseq[c];
  for (int rr = 0; rr < 16; ++rr) {
    int r = (rg << 4) + rr;
    float a = bc + X[r * 68 + c];
    #pragma unroll
    for (int k4 = 0; k4 < 16; ++k4) {
      float4 x = *(const float4*)&X[r * 68 + (k4 << 2)];
      a = fmaf(x.x, Wc[4*k4+0], a); a = fmaf(x.y, Wc[4*k4+1], a);
      a = fmaf(x.z, Wc[4*k4+2], a); a = fmaf(x.w, Wc[4*k4+3], a);
    }
    h[((size_t)(b << 12) + n0 + r) * 64 + c] = a;
  }
}

// ---------------- adjacency MFMA GEMM: single-stage, exp(relu) epilogue ----------------
__global__ __launch_bounds__(256) void k_adjmm(const f16* __restrict__ SEh, const f16* __restrict__ TEh,
                                               f16* __restrict__ A, float* __restrict__ Zpart) {
  __shared__ f16 Al[2][128 * 32];
  __shared__ f16 Bl[2][128 * 32];
  const int t = threadIdx.x, lane = t & 63, w = t >> 6;
  const int m0 = blockIdx.y << 7, j0 = blockIdx.x << 7;
  const int l15 = lane & 15, lhi = lane >> 4;
  const int wm = (w >> 1) << 6, wj = (w & 1) << 6;
  f32x4 acc[4][4] = {};
  const int c0 = (w << 6) + lane;
  const int row0 = c0 >> 2, ko0 = (c0 & 3) << 3;
  const int c1 = c0 + 256;
  const int row1 = c1 >> 2, ko1 = (c1 & 3) << 3;
  const f16* ga0 = SEh + (size_t)(m0 + row0) * 64 + ko0;
  const f16* ga1 = SEh + (size_t)(m0 + row1) * 64 + ko1;
  const f16* gb0 = TEh + (size_t)(j0 + row0) * 64 + ko0;
  const f16* gb1 = TEh + (size_t)(j0 + row1) * 64 + ko1;
  #pragma unroll
  for (int kt = 0; kt < 2; ++kt) {
    const int kof = kt << 5;
    gload16(ga0 + kof, Al[kt] + c0 * 8);
    gload16(ga1 + kof, Al[kt] + c1 * 8);
    gload16(gb0 + kof, Bl[kt] + c0 * 8);
    gload16(gb1 + kof, Bl[kt] + c1 * 8);
  }
  __syncthreads();
  #pragma unroll
  for (int kt = 0; kt < 2; ++kt) {
    half8 af[4], bf[4];
    #pragma unroll
    for (int i = 0; i < 4; ++i) {
      af[i] = *(const half8*)(Al[kt] + (wm + i * 16 + l15) * 32 + lhi * 8);
      bf[i] = *(const half8*)(Bl[kt] + (wj + i * 16 + l15) * 32 + lhi * 8);
    }
    #pragma unroll
    for (int mi = 0; mi < 4; ++mi)
      #pragma unroll
      for (int nj = 0; nj < 4; ++nj)
        acc[mi][nj] = __builtin_amdgcn_mfma_f32_16x16x32_f16(af[mi], bf[nj], acc[mi][nj], 0, 0, 0);
  }
  float rs[4][4];
  #pragma unroll
  for (int mi = 0; mi < 4; ++mi)
    #pragma unroll
    for (int r = 0; r < 4; ++r) rs[mi][r] = 0.f;
  #pragma unroll
  for (int mi = 0; mi < 4; ++mi)
    #pragma unroll
    for (int nj = 0; nj < 4; ++nj)
      #pragma unroll
      for (int r = 0; r < 4; ++r) {
        int row = m0 + wm + mi * 16 + lhi * 4 + r;
        int col = j0 + wj + nj * 16 + l15;
        float e = __expf(fmaxf(acc[mi][nj][r], 0.f));
        f16 eh = (f16)e;
        A[((size_t)row << 12) + col] = eh;
        rs[mi][r] += (float)eh;
      }
  #pragma unroll
  for (int mi = 0; mi < 4; ++mi)
    #pragma unroll
    for (int r = 0; r < 4; ++r) {
      float s = rs[mi][r];
      s += __shfl_xor(s, 1); s += __shfl_xor(s, 2);
      s += __shfl_xor(s, 4); s += __shfl_xor(s, 8);
      rs[mi][r] = s;
    }
  if (l15 == 0) {
    int p = (blockIdx.x << 1) + (w & 1);
    #pragma unroll
    for (int mi = 0; mi < 4; ++mi)
      #pragma unroll
      for (int r = 0; r < 4; ++r)
        Zpart[((size_t)p << 12) + m0 + wm + mi * 16 + lhi * 4 + r] = rs[mi][r];
  }
}

__global__ __launch_bounds__(256) void k_rowz(const float* __restrict__ Zpart, float* __restrict__ rowZ) {
  int row = blockIdx.x * 256 + threadIdx.x;
  float s = 0.f;
  #pragma unroll 8
  for (int p = 0; p < 64; ++p) s += Zpart[((size_t)p << 12) + row];
  rowZ[row] = 1.f / s;
}

// ---------------- big GEMM, 8-phase-style schedule; 4x2 wave decomposition ----------------
#define NKT 32
__global__ __launch_bounds__(512) void k_gemm8(const f16* __restrict__ A, const f16* __restrict__ BT,
                                               f16* __restrict__ Cout) {
  extern __shared__ f16 smem[];
  const int t = threadIdx.x, lane = t & 63, wid = t >> 6;
  const int wr = wid >> 1, wc = wid & 1;
  const int l15 = lane & 15, lhi = lane >> 4;
  const int h7 = l15 & 7;
  const int wgid = blockIdx.x;
  const int nid = (wgid & 7) * 32 + (wgid >> 3);
  const int z = nid >> 7, rem = nid & 127;
  const int m0 = (rem >> 3) << 8;
  const int j0 = (rem & 7) << 7;
  const size_t kbase = (size_t)z << 11;
  f16* __restrict__ Cz = Cout + ((size_t)z << 22);

  const f16* gA[4]; int lA[4];
  #pragma unroll
  for (int i = 0; i < 4; ++i) {
    int s = t + (i << 9), row = s >> 3, sl = (s & 7) ^ (row & 7);
    gA[i] = A + (size_t)(m0 + row) * 4096 + kbase + sl * 8;
    lA[i] = s * 8;
  }
  const f16* gB[2]; int lB[2];
  #pragma unroll
  for (int i = 0; i < 2; ++i) {
    int s = t + (i << 9), row = s >> 3, sl = (s & 7) ^ (row & 7);
    gB[i] = BT + (size_t)(j0 + row) * 4096 + kbase + sl * 8;
    lB[i] = 16384 + s * 8;
  }
  #define SA(buf, kt, i) gload16(gA[i] + (kt) * 64, smem + (buf) * 24576 + lA[i])
  #define SB(buf, kt, i) gload16(gB[i] + (kt) * 64, smem + (buf) * 24576 + lB[i])

  const int rbase = wr << 6;
  const int cbase = wc << 6;
  f32x4 acc[4][4] = {};

  #pragma unroll
  for (int i = 0; i < 4; ++i) SA(0, 0, i);
  #pragma unroll
  for (int i = 0; i < 2; ++i) SB(0, 0, i);
  #pragma unroll
  for (int i = 0; i < 4; ++i) SA(1, 1, i);
  #pragma unroll
  for (int i = 0; i < 2; ++i) SB(1, 1, i);
  asm volatile("s_waitcnt vmcnt(6)" ::: "memory");
  __builtin_amdgcn_sched_barrier(0);
  __builtin_amdgcn_s_barrier();
  __builtin_amdgcn_sched_barrier(0);

  int b0 = 0, b1 = 1, b2 = 2;
  for (int kt = 0; kt < NKT; ++kt) {
    const f16* Ab = smem + b0 * 24576;
    const f16* Bb = Ab + 16384;
    const bool pf = (kt + 2 < NKT);
    {
      half8 af[4], bf[4];
      #pragma unroll
      for (int mi = 0; mi < 4; ++mi) {
        int row = rbase + mi * 16 + l15;
        af[mi] = *(const half8*)(Ab + row * 64 + (lhi ^ h7) * 8);
      }
      #pragma unroll
      for (int nj = 0; nj < 4; ++nj) {
        int row = cbase + nj * 16 + l15;
        bf[nj] = *(const half8*)(Bb + row * 64 + (lhi ^ h7) * 8);
      }
      if (pf) { SA(b2, kt + 2, 0); SA(b2, kt + 2, 1); SA(b2, kt + 2, 2); }
      __builtin_amdgcn_s_setprio(1);
      #pragma unroll
      for (int mi = 0; mi < 4; ++mi)
        #pragma unroll
        for (int nj = 0; nj < 4; ++nj)
          acc[mi][nj] = __builtin_amdgcn_mfma_f32_16x16x32_f16(af[mi], bf[nj], acc[mi][nj], 0, 0, 0);
      __builtin_amdgcn_s_setprio(0);
    }
    __builtin_amdgcn_s_barrier();
    __builtin_amdgcn_sched_barrier(0);
    {
      half8 af[4], bf[4];
      #pragma unroll
      for (int mi = 0; mi < 4; ++mi) {
        int row = rbase + mi * 16 + l15;
        af[mi] = *(const half8*)(Ab + row * 64 + ((4 + lhi) ^ h7) * 8);
      }
      #pragma unroll
      for (int nj = 0; nj < 4; ++nj) {
        int row = cbase + nj * 16 + l15;
        bf[nj] = *(const half8*)(Bb + row * 64 + ((4 + lhi) ^ h7) * 8);
      }
      if (pf) { SA(b2, kt + 2, 3); SB(b2, kt + 2, 0); SB(b2, kt + 2, 1); }
      __builtin_amdgcn_s_setprio(1);
      #pragma unroll
      for (int mi = 0; mi < 4; ++mi)
        #pragma unroll
        for (int nj = 0; nj < 4; ++nj)
          acc[mi][nj] = __builtin_amdgcn_mfma_f32_16x16x32_f16(af[mi], bf[nj], acc[mi][nj], 0, 0, 0);
      __builtin_amdgcn_s_setprio(0);
    }
    if (kt < NKT - 2)       asm volatile("s_waitcnt vmcnt(6)" ::: "memory");
    else if (kt == NKT - 2) asm volatile("s_waitcnt vmcnt(0)" ::: "memory");
    __builtin_amdgcn_sched_barrier(0);
    __builtin_amdgcn_s_barrier();
    __builtin_amdgcn_sched_barrier(0);
    int tb = b0; b0 = b1; b1 = b2; b2 = tb;
  }
  #undef SA
  #undef SB
  #pragma unroll
  for (int mi = 0; mi < 4; ++mi)
    #pragma unroll
    for (int nj = 0; nj < 4; ++nj)
      #pragma unroll
      for (int r = 0; r < 4; ++r) {
        int row = m0 + rbase + mi * 16 + (lhi << 2) + r;
        int col = j0 + cbase + nj * 16 + l15;
        Cz[(size_t)row * 1024 + col] = (f16)acc[mi][nj][r];
      }
}

// ---------------- fused prep: Wgh1, Wgh2, W0h, SE cast, TE cast ----------------
template<int H, int NP>
__device__ __forceinline__ void wprep_body(const float* __restrict__ Wg, const float* __restrict__ asrc,
                                           const float* __restrict__ adst, const float* __restrict__ Wl,
                                           f16* __restrict__ Wgh, int bid, int t) {
  const int WL0 = H * 64 + 16;
  for (int i = bid * 256 + t; i < NP * 64; i += 16 * 256) {
    int j = i >> 6, k = i & 63;
    float v;
    if (j < H * 64) {
      v = Wg[(size_t)k * (H * 64) + j];
    } else if (j < H * 64 + 2 * H) {
      int cc = j - H * 64, hh = cc >> 1;
      const float* a = ((cc & 1) ? adst : asrc) + (hh << 6);
      const float* wrow = Wg + (size_t)k * (H * 64) + (hh << 6);
      float s = 0.f;
      #pragma unroll 16
      for (int c = 0; c < 64; ++c) s = fmaf(wrow[c], a[c], s);
      v = s;
    } else if (j >= WL0 && j < WL0 + 64) {
      v = Wl[(k << 6) + (j - WL0)];
    } else v = 0.f;
    Wgh[(size_t)j * 64 + k] = (f16)v;
  }
}

__global__ __launch_bounds__(256) void k_allprep(
    const float* __restrict__ Wg1, const float* __restrict__ as1, const float* __restrict__ ad1,
    const float* __restrict__ Wl1, f16* __restrict__ Wgh1,
    const float* __restrict__ Wg2, const float* __restrict__ as2, const float* __restrict__ ad2,
    const float* __restrict__ Wl2, f16* __restrict__ Wgh2,
    const float* __restrict__ Wl0, const float* __restrict__ Wo, f16* __restrict__ W0h,
    const float* __restrict__ SE, const float* __restrict__ TE,
    f16* __restrict__ SEh, f16* __restrict__ TEh) {
  __shared__ float X[64 * 65];
  int bid = blockIdx.x, t = threadIdx.x;
  if (bid < 16) { wprep_body<3, 272>(Wg1, as1, ad1, Wl1, Wgh1, bid, t); return; }
  if (bid < 32) { wprep_body<1, 144>(Wg2, as2, ad2, Wl2, Wgh2, bid - 16, t); return; }
  if (bid < 40) {
    for (int i = (bid - 32) * 256 + t; i < 128 * 64; i += 8 * 256) {
      int j = i >> 6, k = i & 63;
      float v = (j < 64) ? Wl0[(k << 6) + j] : Wo[(k << 6) + (j - 64)];
      W0h[(size_t)j * 64 + k] = (f16)v;
    }
    return;
  }
  if (bid < 296) {                     // SE cast
    int i = ((bid - 40) * 256 + t) * 4;
    float4 v = *(const float4*)(SE + i);
    f16 o[4] = {(f16)v.x, (f16)v.y, (f16)v.z, (f16)v.w};
    *(uint64_t*)(SEh + i) = *(uint64_t*)o;
    return;
  }
  // TE transpose-cast
  int j0 = (bid - 296) << 6;
  #pragma unroll
  for (int i = 0; i < 16; ++i) {
    int idx = t + (i << 8);
    int k = idx >> 6, jl = idx & 63;
    X[jl * 65 + k] = TE[((size_t)k << 12) + j0 + jl];
  }
  __syncthreads();
  int jl = t >> 2, kg = t & 3;
  f16 o[16];
  #pragma unroll
  for (int i = 0; i < 16; ++i) o[i] = (f16)X[jl * 65 + (kg << 4) + i];
  f16* dst = TEh + ((size_t)(j0 + jl) << 6) + (kg << 4);
  *(uint64_t*)(dst + 0) = *(uint64_t*)(o + 0);
  *(uint64_t*)(dst + 4) = *(uint64_t*)(o + 4);
  *(uint64_t*)(dst + 8) = *(uint64_t*)(o + 8);
  *(uint64_t*)(dst + 12) = *(uint64_t*)(o + 12);
}

// ---------------- xp = h @ Wg via MFMA + als/ald + HWlT ----------------
template<int H, int NP>
__global__ __launch_bounds__(256) void k_xpmm(const float* __restrict__ h, const f16* __restrict__ Wgh,
                                              f16* __restrict__ xp, float* __restrict__ als,
                                              float* __restrict__ ald, f16* __restrict__ HWlT) {
  const int WL0 = H * 64 + 16, JW0 = WL0 / 16, NT = NP / 16;
  __shared__ f16 Ah[64 * 72];
  __shared__ f16 Bh[NP * 72];
  __shared__ f16 stage[64 * 72];
  const int t = threadIdx.x, lane = t & 63, w = t >> 6;
  const size_t r0 = (size_t)blockIdx.x * 64;
  const int b = (int)(r0 >> 12), n0 = (int)(r0 & 4095);
  #pragma unroll
  for (int i = 0; i < 4; ++i) {
    int idx = t + (i << 8);
    int row = idx >> 4, k4 = (idx & 15) << 2;
    float4 v = *(const float4*)&h[(r0 + row) * 64 + k4];
    f16 o[4] = {(f16)v.x, (f16)v.y, (f16)v.z, (f16)v.w};
    *(uint64_t*)&Ah[row * 72 + k4] = *(uint64_t*)o;
  }
  for (int i = t; i < NP * 16; i += 256) {
    int row = i >> 4, k4 = (i & 15) << 2;
    *(uint64_t*)&Bh[row * 72 + k4] = *(const uint64_t*)&Wgh[(size_t)row * 64 + k4];
  }
  __syncthreads();
  const int l15 = lane & 15, lhi = lane >> 4;
  f32x4 acc[NT] = {};
  #pragma unroll
  for (int kk = 0; kk < 2; ++kk) {
    half8 af = *(const half8*)&Ah[(w * 16 + l15) * 72 + kk * 32 + lhi * 8];
    #pragma unroll
    for (int j = 0; j < NT; ++j) {
      half8 bf = *(const half8*)&Bh[(j * 16 + l15) * 72 + kk * 32 + lhi * 8];
      acc[j] = __builtin_amdgcn_mfma_f32_16x16x32_f16(af, bf, acc[j], 0, 0, 0);
    }
  }
  const int rl = w * 16 + lhi * 4;
  #pragma unroll
  for (int j = 0; j < NT; ++j) {
    int col = j * 16 + l15;
    if (j * 16 + 15 < H * 64) {
      #pragma unroll
      for (int r = 0; r < 4; ++r) {
        if (H == 3) xp[(r0 + rl + r) * 256 + ((col & 63) << 2) + (col >> 6)] = (f16)acc[j][r];
        else        xp[(r0 + rl + r) * 64 + col] = (f16)acc[j][r];
      }
    } else if (j < JW0) {
      int cc = col - H * 64;
      if (cc >= 0 && cc < 2 * H) {
        int hh = cc >> 1;
        #pragma unroll
        for (int r = 0; r < 4; ++r) {
          if (cc & 1) ald[(r0 + rl + r) * H + hh] = acc[j][r];
          else        als[(r0 + rl + r) * H + hh] = acc[j][r];
        }
      }
    } else {
      int e = col - WL0;
      f16 o[4] = {(f16)acc[j][0], (f16)acc[j][1], (f16)acc[j][2], (f16)acc[j][3]};
      *(uint64_t*)&stage[e * 72 + rl] = *(uint64_t*)o;
    }
  }
  __syncthreads();
  {
    int e = t >> 2, seg = (t & 3) << 4;
    float4 v0 = *(const float4*)&stage[e * 72 + seg];
    float4 v1 = *(const float4*)&stage[e * 72 + seg + 8];
    f16* dst = HWlT + (((size_t)((b << 6) + e)) << 12) + n0 + seg;
    *(float4*)dst = v0;
    *(float4*)(dst + 8) = v1;
  }
}

// ---------------- layer-0 prep: h @ [Wl0|Wo] -> HWlT + orig ----------------
__global__ __launch_bounds__(256) void k_prep0(const float* __restrict__ h, const f16* __restrict__ W0h,
                                               f16* __restrict__ HWlT, f16* __restrict__ orig) {
  __shared__ f16 Ah[64 * 72];
  __shared__ f16 Bh[128 * 72];
  __shared__ f16 stage[64 * 72];
  const int t = threadIdx.x, lane = t & 63, w = t >> 6;
  const size_t r0 = (size_t)blockIdx.x * 64;
  const int b = (int)(r0 >> 12), n0 = (int)(r0 & 4095);
  #pragma unroll
  for (int i = 0; i < 4; ++i) {
    int idx = t + (i << 8);
    int row = idx >> 4, k4 = (idx & 15) << 2;
    float4 v = *(const float4*)&h[(r0 + row) * 64 + k4];
    f16 o[4] = {(f16)v.x, (f16)v.y, (f16)v.z, (f16)v.w};
    *(uint64_t*)&Ah[row * 72 + k4] = *(uint64_t*)o;
  }
  for (int i = t; i < 128 * 16; i += 256) {
    int row = i >> 4, k4 = (i & 15) << 2;
    *(uint64_t*)&Bh[row * 72 + k4] = *(const uint64_t*)&W0h[(size_t)row * 64 + k4];
  }
  __syncthreads();
  const int l15 = lane & 15, lhi = lane >> 4;
  f32x4 acc[8] = {};
  #pragma unroll
  for (int kk = 0; kk < 2; ++kk) {
    half8 af = *(const half8*)&Ah[(w * 16 + l15) * 72 + kk * 32 + lhi * 8];
    #pragma unroll
    for (int j = 0; j < 8; ++j) {
      half8 bf = *(const half8*)&Bh[(j * 16 + l15) * 72 + kk * 32 + lhi * 8];
      acc[j] = __builtin_amdgcn_mfma_f32_16x16x32_f16(af, bf, acc[j], 0, 0, 0);
    }
  }
  const int rl = w * 16 + lhi * 4;
  #pragma unroll
  for (int j = 0; j < 8; ++j) {
    int col = j * 16 + l15;
    if (j < 4) {
      f16 o[4] = {(f16)acc[j][0], (f16)acc[j][1], (f16)acc[j][2], (f16)acc[j][3]};
      *(uint64_t*)&stage[col * 72 + rl] = *(uint64_t*)o;
    } else {
      #pragma unroll
      for (int r = 0; r < 4; ++r)
        orig[(r0 + rl + r) * 64 + (col - 64)] = (f16)acc[j][r];
    }
  }
  __syncthreads();
  {
    int e = t >> 2, seg = (t & 3) << 4;
    float4 v0 = *(const float4*)&stage[e * 72 + seg];
    float4 v1 = *(const float4*)&stage[e * 72 + seg + 8];
    f16* dst = HWlT + (((size_t)((b << 6) + e)) << 12) + n0 + seg;
    *(float4*)dst = v0;
    *(float4*)(dst + 8) = v1;
  }
}

// ---------------- Mals[b][h] = max_n als ----------------
template<int H>
__global__ __launch_bounds__(256) void k_maxals(const float* __restrict__ als, float* __restrict__ Mals) {
  __shared__ float red[256];
  int b = blockIdx.x, t = threadIdx.x;
  size_t rbase = (size_t)b << 12;
  for (int h = 0; h < H; ++h) {
    float m = -1e30f;
    for (int n = t; n < NN; n += 256) m = fmaxf(m, als[(rbase + n) * H + h]);
    red[t] = m;
    __syncthreads();
    for (int d = 128; d; d >>= 1) {
      if (t < d) red[t] = fmaxf(red[t], red[t + d]);
      __syncthreads();
    }
    if (t == 0) Mals[b * H + h] = red[0];
    __syncthreads();
  }
}

// ---------------- edge weights (H==3: stride-4 padded) ----------------
template<int H>
__global__ __launch_bounds__(256) void k_wts(const float* __restrict__ als, const float* __restrict__ ald,
                                             const float* __restrict__ Mals, const int* __restrict__ esrc,
                                             const int* __restrict__ edst, float* __restrict__ wts) {
  const int WST = (H == 3) ? 4 : 1;
  int t = threadIdx.x, lane = t & 63, w = t >> 6;
  int gw = blockIdx.x * 4 + w;
  int b = gw & 15;
  int p = ((gw >> 4) << 6) + lane;
  size_t rbase = (size_t)b << 12;
  int s = esrc[p], n = edst[p];
  float* dst = wts + ((size_t)b * ETOT + p) * WST;
  #pragma unroll
  for (int h = 0; h < H; ++h) {
    float ad = ald[(rbase + n) * H + h];
    float B = Mals[b * H + h] + ad;
    float T = B > 0.f ? B : 0.2f * B;
    float ev = als[(rbase + s) * H + h] + ad;
    ev = ev > 0.f ? ev : 0.2f * ev;
    dst[h] = __expf(ev - T);
  }
}

// ---------------- GAT aggregation + fused gate combine; XCD-pinned batches ----------------
// Block mapping: b = ((blk&7)<<1)|((blk>>3)&1) -> HW round-robin (blk%8 -> XCD) pins each
// batch's xp/wts/gp/h slices (~10 MB) to 2-batches-per-XCD L2 working set.
template<int H, int ACT>   // ACT 0: leaky 0.01, 1: relu
__global__ __launch_bounds__(256) void k_aggc(const f16* __restrict__ xp, const float* __restrict__ wts,
                                              const int* __restrict__ offs, const int* __restrict__ cnt,
                                              const int* __restrict__ esrc, const float* __restrict__ bg,
                                              const float* __restrict__ h, const f16* __restrict__ gp,
                                              const float* __restrict__ rowZ, const float* __restrict__ bl,
                                              float* __restrict__ hout) {
  const int WST = (H == 3) ? 4 : 1;
  __shared__ float wbuf[4][64 * WST];
  __shared__ int   sbuf[4][64];
  int t = threadIdx.x, lane = t & 63, wv = t >> 6;
  int blk = blockIdx.x;
  int b = ((blk & 7) << 1) | ((blk >> 3) & 1);
  int n = ((blk >> 4) << 2) + wv;
  size_t rbase = (size_t)b << 12;
  int o = offs[n], c = cnt[n];
  const float* wsrc = wts + ((size_t)b * ETOT + o) * WST;
  float z[H], acc[H];
  #pragma unroll
  for (int hh = 0; hh < H; ++hh) { z[hh] = 0.f; acc[hh] = 0.f; }
  for (int e0 = 0; e0 < c; e0 += 64) {
    int ce = min(64, c - e0);
    if (lane < ce) {
      sbuf[wv][lane] = esrc[o + e0 + lane];
      if (H == 3) *(float4*)&wbuf[wv][lane * 4] = *(const float4*)&wsrc[(size_t)(e0 + lane) * 4];
      else        wbuf[wv][lane] = wsrc[e0 + lane];
    }
    #pragma unroll 4
    for (int e = 0; e < ce; ++e) {
      int s = sbuf[wv][e];
      if (H == 3) {
        float4 w4 = *(const float4*)&wbuf[wv][e * 4];
        f16x4 q = *(const f16x4*)(xp + (((size_t)(rbase + s)) << 8) + (lane << 2));
        z[0] += w4.x; acc[0] = fmaf(w4.x, (float)q[0], acc[0]);
        z[1] += w4.y; acc[1] = fmaf(w4.y, (float)q[1], acc[1]);
        z[2] += w4.z; acc[2] = fmaf(w4.z, (float)q[2], acc[2]);
      } else {
        float wv_ = wbuf[wv][e];
        float xv = (float)xp[(((size_t)(rbase + s)) << 6) + lane];
        z[0] += wv_; acc[0] = fmaf(wv_, xv, acc[0]);
      }
    }
  }
  float r = 0.f;
  #pragma unroll
  for (int hh = 0; hh < H; ++hh) r += acc[hh] / z[hh];
  float cv = r * (1.f / H) + bg[lane];
  size_t ga = ((size_t)n << 10) + (b << 6) + lane;
  float zi = rowZ[n];
  float g0 = (float)gp[ga], g1 = (float)gp[ga + (size_t)(4096 * 1024)];
  float g = 1.f / (1.f + __expf(-((g0 + g1) * zi + bl[lane])));
  size_t ridx = ((rbase + n) << 6) + lane;
  float hv = h[ridx];
  float act = ACT ? fmaxf(cv, 0.f) : (cv > 0.f ? cv : 0.01f * cv);
  hout[ridx] = act * g + hv * (1.f - g);
}

// ---------------- layer-0 combine: pure elementwise ----------------
__global__ __launch_bounds__(256) void k_comb0e(const float* __restrict__ h, const f16* __restrict__ gp,
                                                const float* __restrict__ rowZ, const f16* __restrict__ orig,
                                                const float* __restrict__ bl, const float* __restrict__ bo,
                                                float* __restrict__ hout) {
  for (size_t i4 = (size_t)blockIdx.x * 256 + threadIdx.x; i4 < (size_t)ROWS * 16; i4 += (size_t)2048 * 256) {
    size_t i = i4 * 4;
    int d = (int)(i & 63), n = (int)((i >> 6) & 4095), b = (int)(i >> 18);
    size_t ga = ((size_t)n << 10) + (b << 6) + d;
    float zi = rowZ[n];
    f16x4 g0 = *(const f16x4*)&gp[ga];
    f16x4 g1 = *(const f16x4*)&gp[ga + (size_t)(4096 * 1024)];
    f16x4 og = *(const f16x4*)&orig[i];
    float4 hv = *(const float4*)&h[i];
    float4 o;
    float* op = &o.x;
    const float* hp = &hv.x;
    #pragma unroll
    for (int r = 0; r < 4; ++r) {
      float g = 1.f / (1.f + __expf(-(((float)g0[r] + (float)g1[r]) * zi + bl[d + r])));
      float orv = (float)og[r] + bo[d + r];
      op[r] = tanhf(hp[r]) * g + orv * (1.f - g);
    }
    *(float4*)&hout[i] = o;
  }
}

// ---------------- host launch ----------------
extern "C" void kernel_launch(void* const* d_in, const int* in_sizes, int n_in,
                              void* d_out, int out_size, void* d_ws, size_t ws_size,
                              hipStream_t stream) {
  (void)in_sizes; (void)n_in; (void)out_size; (void)ws_size;
  const float* inp  = (const float*)d_in[0];
  const int*   ei   = (const int*)d_in[1];
  const float* Wseq = (const float*)d_in[2];
  const float* bseq = (const float*)d_in[3];
  const float* SE   = (const float*)d_in[4];
  const float* TE   = (const float*)d_in[5];
  const float* Wg[3]   = {(const float*)d_in[6],  (const float*)d_in[12], (const float*)d_in[18]};
  const float* asrc[3] = {(const float*)d_in[7],  (const float*)d_in[13], (const float*)d_in[19]};
  const float* adst[3] = {(const float*)d_in[8],  (const float*)d_in[14], (const float*)d_in[20]};
  const float* bgp[3]  = {(const float*)d_in[9],  (const float*)d_in[15], (const float*)d_in[21]};
  const float* Wl[3]   = {(const float*)d_in[10], (const float*)d_in[16], (const float*)d_in[22]};
  const float* bl[3]   = {(const float*)d_in[11], (const float*)d_in[17], (const float*)d_in[23]};
  const float* Wo = (const float*)d_in[24];
  const float* bo = (const float*)d_in[25];
  float* out = (float*)d_out;

  uint8_t* ws = (uint8_t*)d_ws;
  size_t o = 0;
  auto nxt = [&](size_t sz) { void* p = ws + o; o += (sz + 255) & ~(size_t)255; return p; };
  f16*   Af   = (f16*)  nxt((size_t)NN * NN * sizeof(f16));            // 32 MB
  f16*   HWlT = (f16*)  nxt((size_t)1024 * NN * sizeof(f16));          // 8 MB
  float* h    = (float*)nxt((size_t)ROWS * 64 * 4);                    // 16 MB
  f16*   gp   = (f16*)  nxt((size_t)KSPLIT * NN * 1024 * sizeof(f16)); // 16 MB
  f16*   xp   = (f16*)  nxt((size_t)ROWS * 256 * sizeof(f16));         // 32 MB (H=3 interleaved)
  f16*   orig = (f16*)  nxt((size_t)ROWS * 64 * sizeof(f16));          // 8 MB
  float* als  = (float*)nxt((size_t)ROWS * 3 * 4);
  float* ald  = (float*)nxt((size_t)ROWS * 3 * 4);
  float* rowZ = (float*)nxt((size_t)NN * 4);
  float* Zpart= (float*)nxt((size_t)64 * NN * 4);                      // 1 MB
  f16*   SEh  = (f16*)  nxt((size_t)NN * 64 * sizeof(f16));
  f16*   TEh  = (f16*)  nxt((size_t)NN * 64 * sizeof(f16));
  f16*   Wgh1 = (f16*)  nxt((size_t)288 * 64 * sizeof(f16));
  f16*   Wgh2 = (f16*)  nxt((size_t)144 * 64 * sizeof(f16));
  f16*   W0h  = (f16*)  nxt((size_t)128 * 64 * sizeof(f16));
  float* wts  = (float*)nxt((size_t)NB * ETOT * 4 * 4);                // 9.4 MB (stride-4)
  float* Mals = (float*)nxt((size_t)NB * 3 * 4);
  int*   cnt  = (int*)  nxt((size_t)NN * 4);
  int*   curp = (int*)  nxt((size_t)NN * 4);
  int*   offs = (int*)  nxt((size_t)NN * 4);
  int*   esrc = (int*)  nxt((size_t)ETOT * 4);
  int*   edst = (int*)  nxt((size_t)ETOT * 4);

  static bool attr_set = false;
  if (!attr_set) {
    hipFuncSetAttribute((const void*)k_gemm8, hipFuncAttributeMaxDynamicSharedMemorySize, 147456);
    attr_set = true;
  }

  dim3 blk(256);
  // CSR build + independent prep (incl. SE/TE casts)
  k_zero2<<<32, blk, 0, stream>>>(cnt, curp);
  k_count<<<144, blk, 0, stream>>>(ei, cnt);
  k_scan<<<1, blk, 0, stream>>>(cnt, offs);
  k_fill<<<144, blk, 0, stream>>>(ei, offs, curp, esrc, edst);
  k_allprep<<<360, blk, 0, stream>>>(Wg[1], asrc[1], adst[1], Wl[1], Wgh1,
                                     Wg[2], asrc[2], adst[2], Wl[2], Wgh2,
                                     Wl[0], Wo, W0h, SE, TE, SEh, TEh);
  // h0 + adjacency
  k_seq<<<1024, blk, 0, stream>>>(inp, Wseq, bseq, h);
  k_adjmm<<<dim3(32, 32), blk, 0, stream>>>(SEh, TEh, Af, Zpart);
  k_rowz<<<16, blk, 0, stream>>>(Zpart, rowZ);
  // ---- layer 0 ----
  k_prep0<<<1024, blk, 0, stream>>>(h, W0h, HWlT, orig);
  k_gemm8<<<256, 512, 147456, stream>>>(Af, HWlT, gp);
  k_comb0e<<<2048, blk, 0, stream>>>(h, gp, rowZ, orig, bl[0], bo, h);
  // ---- layer 1 ----
  k_xpmm<3, 272><<<1024, blk, 0, stream>>>(h, Wgh1, xp, als, ald, HWlT);
  k_maxals<3><<<16, blk, 0, stream>>>(als, Mals);
  k_wts<3><<<2304, blk, 0, stream>>>(als, ald, Mals, esrc, edst, wts);
  k_gemm8<<<256, 512, 147456, stream>>>(Af, HWlT, gp);
  k_aggc<3, 0><<<16384, blk, 0, stream>>>(xp, wts, offs, cnt, esrc, bgp[1], h, gp, rowZ, bl[1], h);
  // ---- layer 2 ----
  k_xpmm<1, 144><<<1024, blk, 0, stream>>>(h, Wgh2, xp, als, ald, HWlT);
  k_maxals<1><<<16, blk, 0, stream>>>(als, Mals);
  k_wts<1><<<2304, blk, 0, stream>>>(als, ald, Mals, esrc, edst, wts);
  k_gemm8<<<256, 512, 147456, stream>>>(Af, HWlT, gp);
  k_aggc<1, 1><<<16384, blk, 0, stream>>>(xp, wts, offs, cnt, esrc, bgp[2], h, gp, rowZ, bl[2], out);
}